// Round 8
// baseline (1234.656 us; speedup 1.0000x reference)
//
#include <hip/hip_runtime.h>
#include <float.h>
#include <math.h>
#include <stdint.h>

#define LT 1360
#define BB 4
#define DM 512
#define NHH 8
#define NBLE 2785280   // BB*LT*512 elements
#define MBW 24         // mask words (uint64) per row
#define QSCALE 0.18033688f   // 0.125 * log2(e)

typedef __attribute__((ext_vector_type(8))) short short8;
typedef __attribute__((ext_vector_type(4))) float f32x4;
typedef unsigned long long u64;

__device__ __forceinline__ ushort f2b(float x){
    uint32_t u = __float_as_uint(x);
    return (ushort)((u + 0x7fffu + ((u >> 16) & 1u)) >> 16);
}
__device__ __forceinline__ float b2f(ushort u){
    return __uint_as_float(((uint32_t)u) << 16);
}

// semantic sim buffer layout (per batch)
#define SG0 0
#define SG1 1048576
#define SG2 (SG1 + 65536)
#define SG3 (SG2 + 4096)
#define SBT (SG3 + 256)

__device__ __forceinline__ void blk_info(int i, int& bi, int& st, int& n){
    if (i < 1024){ bi = 0; st = 0;    n = 1024; }
    else if (i < 1280){ bi = 1; st = 1024; n = 256; }
    else if (i < 1344){ bi = 2; st = 1280; n = 64; }
    else { bi = 3; st = 1344; n = 16; }
}

// ---------------- temporal allowed-index lists
__global__ __launch_bounds__(256)
void build_tidx(int* __restrict__ idx, int* __restrict__ cnt){
    int i = blockIdx.x * 256 + threadIdx.x;
    if (i >= LT) return;
    int bi, st, n; blk_info(i, bi, st, n);
    int c = 0; int* row = idx + i * 12;
    int lo = (i - 2 > st) ? i - 2 : st;
    int hi = (i + 2 < st + n - 1) ? i + 2 : st + n - 1;
    for (int j = lo; j <= hi; j++) row[c++] = j;
    if (bi < 3) row[c++] = st + n + (i - st) / 4;
    if (bi > 0){
        int stc = st - n * 4;
        int base = stc + (i - st) * 4;
        for (int t = 0; t < 4; t++) row[c++] = base + t;
    }
    cnt[i] = c;
}

// ---------------- weight transpose+cast: Wd[n*K+k] = bf16(Ws[k*N+n])
__global__ __launch_bounds__(256)
void wtrans(const float* __restrict__ W, ushort* __restrict__ Wt, int K, int N, long dstStride){
    int mat = blockIdx.z;
    const float* Ws = W + (size_t)mat * K * N;
    ushort* Wd = Wt + (size_t)mat * dstStride;
    int k0 = blockIdx.y << 6, n0 = blockIdx.x << 6;
    __shared__ ushort t[64][72];
    int tid = threadIdx.x;
    #pragma unroll
    for (int p = 0; p < 4; p++){
        int idx = tid + (p << 8);
        int r = idx >> 4, c4 = (idx & 15) << 2;
        float4 v = *(const float4*)(Ws + (size_t)(k0 + r) * N + n0 + c4);
        t[c4+0][r] = f2b(v.x); t[c4+1][r] = f2b(v.y);
        t[c4+2][r] = f2b(v.z); t[c4+3][r] = f2b(v.w);
    }
    __syncthreads();
    #pragma unroll
    for (int p = 0; p < 4; p++){
        int idx = tid + (p << 8);
        int r = idx >> 4, c4 = (idx & 15) << 2;
        *(uint2*)&Wd[(size_t)(n0 + r) * K + k0 + c4] = *(uint2*)&t[r][c4];
    }
}

// ---------------- conv weight repack+cast
__global__ __launch_bounds__(256)
void wconv(const float* __restrict__ cw, ushort* __restrict__ wt){
    int conv = blockIdx.y;
    const float* src = cw + (size_t)conv * 512 * 512 * 4;
    ushort* dst = wt + (size_t)conv * 2048 * 512;
    int idx = blockIdx.x * 256 + threadIdx.x;
    int o = idx >> 11, rest = idx & 2047;
    int k = rest >> 9, ii = rest & 511;
    dst[idx] = f2b(src[((size_t)(o << 9) + ii) * 4 + k]);
}

// ---------------- bf16 MFMA GEMM, 64x128 tile, BK=32, 256 thr / 4 waves
// wave w: cols w*32..w*32+31, all 64 rows. 8 MFMA per k-iter per wave.
// act: 0 none, 1 ELU(cscale*v), 2 relu
// omode: 0 f32 out (+row remap), 1 bf16 out, 2 bf16 V^T out, 3 fused QKV out (N=1536, Q scaled)
__global__ __launch_bounds__(256)
void gemm_bf16(const float* __restrict__ A, const ushort* __restrict__ Bw,
               const float* __restrict__ bias, const float* __restrict__ Rres,
               void* __restrict__ Cout, int M, int N, int K,
               int act, int omode, int mpb, int orpb, int ooff)
{
    __shared__ ushort As[64][40];
    __shared__ ushort Bs[128][40];
    int tid = threadIdx.x;
    int lane = tid & 63, w = tid >> 6, quad = lane >> 4, l15 = lane & 15;
    int gm = blockIdx.y << 6, gn = blockIdx.x << 7;
    int arow = tid >> 2, ac8 = (tid & 3) << 3;
    int brow = tid >> 1, bc16 = (tid & 1) << 4;
    f32x4 acc[4][2];
    #pragma unroll
    for (int mi = 0; mi < 4; mi++)
        #pragma unroll
        for (int ni = 0; ni < 2; ni++)
            acc[mi][ni] = (f32x4){0.f,0.f,0.f,0.f};
    const float* Ap = A + (size_t)(gm + arow) * K;
    const ushort* Bp = Bw + (size_t)(gn + brow) * K;
    for (int k0 = 0; k0 < K; k0 += 32){
        float4 a0 = *(const float4*)(Ap + k0 + ac8);
        float4 a1 = *(const float4*)(Ap + k0 + ac8 + 4);
        uint4 av;
        av.x = (uint32_t)f2b(a0.x) | ((uint32_t)f2b(a0.y) << 16);
        av.y = (uint32_t)f2b(a0.z) | ((uint32_t)f2b(a0.w) << 16);
        av.z = (uint32_t)f2b(a1.x) | ((uint32_t)f2b(a1.y) << 16);
        av.w = (uint32_t)f2b(a1.z) | ((uint32_t)f2b(a1.w) << 16);
        *(uint4*)&As[arow][ac8] = av;
        *(uint4*)&Bs[brow][bc16]     = *(const uint4*)(Bp + k0 + bc16);
        *(uint4*)&Bs[brow][bc16 + 8] = *(const uint4*)(Bp + k0 + bc16 + 8);
        __syncthreads();
        short8 af[4], bf[2];
        #pragma unroll
        for (int mi = 0; mi < 4; mi++) af[mi] = *(const short8*)&As[(mi << 4) + l15][quad << 3];
        #pragma unroll
        for (int ni = 0; ni < 2; ni++) bf[ni] = *(const short8*)&Bs[(w << 5) + (ni << 4) + l15][quad << 3];
        #pragma unroll
        for (int mi = 0; mi < 4; mi++)
            #pragma unroll
            for (int ni = 0; ni < 2; ni++)
                acc[mi][ni] = __builtin_amdgcn_mfma_f32_16x16x32_bf16(af[mi], bf[ni], acc[mi][ni], 0, 0, 0);
        __syncthreads();
    }
    const float cscale = 0.9999950000375f;
    #pragma unroll
    for (int mi = 0; mi < 4; mi++){
        #pragma unroll
        for (int r = 0; r < 4; r++){
            int row = gm + (mi << 4) + (quad << 2) + r;
            #pragma unroll
            for (int ni = 0; ni < 2; ni++){
                int col = gn + (w << 5) + (ni << 4) + l15;
                float v = acc[mi][ni][r];
                if (bias) v += bias[col];
                if (Rres) v += Rres[(size_t)row * N + col];
                if (act == 1){ v *= cscale; v = (v > 0.f) ? v : expm1f(v); }
                else if (act == 2){ v = fmaxf(v, 0.f); }
                if (omode == 0){
                    int orow = mpb ? (row / mpb) * orpb + ooff + (row % mpb) : row;
                    ((float*)Cout)[(size_t)orow * N + col] = v;
                } else if (omode == 1){
                    ((ushort*)Cout)[(size_t)row * N + col] = f2b(v);
                } else if (omode == 2){
                    int bb = row / LT, ii = row - bb * LT;
                    ((ushort*)Cout)[((size_t)(bb * 512 + col)) * LT + ii] = f2b(v);
                } else {
                    int seg = col >> 9, c5 = col & 511;
                    ushort* Ob = (ushort*)Cout;
                    if (seg == 0)      Ob[(size_t)row * 512 + c5] = f2b(v * QSCALE);
                    else if (seg == 1) Ob[(size_t)2*NBLE + (size_t)row * 512 + c5] = f2b(v);
                    else {
                        int bb = row / LT, ii = row - bb * LT;
                        Ob[(size_t)4*NBLE + ((size_t)(bb * 512 + c5)) * LT + ii] = f2b(v);
                    }
                }
            }
        }
    }
}

// ---------------- semantic sim via split-bf16 MFMA (hi/lo precomputed)
__global__ __launch_bounds__(256)
void sim_mfma(const ushort* __restrict__ XH, const ushort* __restrict__ XL,
              float* __restrict__ SIM){
    __shared__ ushort Ah[64][40], Al[64][40], Bh[64][40], Bl[64][40];
    int x = blockIdx.x, b = blockIdx.y;
    int ti, tj, st, n, goff;
    if (x < 256){ ti = x >> 4; tj = x & 15; st = 0; n = 1024; goff = SG0; }
    else if (x < 272){ int y = x - 256; ti = y >> 2; tj = y & 3; st = 1024; n = 256; goff = SG1; }
    else if (x == 272){ ti = 0; tj = 0; st = 1280; n = 64; goff = SG2; }
    else { ti = 0; tj = 0; st = 1344; n = 16; goff = SG3; }
    const ushort* XbH = XH + (((size_t)b * LT + st) << 9);
    const ushort* XbL = XL + (((size_t)b * LT + st) << 9);
    float* Cb = SIM + (size_t)b * SBT + goff;
    int gm = ti << 6, gn = tj << 6;
    int tid = threadIdx.x;
    int lane = tid & 63, w = tid >> 6, quad = lane >> 4, l15 = lane & 15;
    int wr = (w >> 1) << 5, wc = (w & 1) << 5;
    int srow = tid >> 2, sc8 = (tid & 3) << 3;
    int ra = gm + srow; if (ra > n - 1) ra = n - 1;
    int rb = gn + srow; if (rb > n - 1) rb = n - 1;
    f32x4 acc[2][2];
    #pragma unroll
    for (int mi = 0; mi < 2; mi++)
        #pragma unroll
        for (int ni = 0; ni < 2; ni++)
            acc[mi][ni] = (f32x4){0.f,0.f,0.f,0.f};
    for (int k0 = 0; k0 < 512; k0 += 32){
        *(uint4*)&Ah[srow][sc8] = *(const uint4*)(XbH + ((size_t)ra << 9) + k0 + sc8);
        *(uint4*)&Al[srow][sc8] = *(const uint4*)(XbL + ((size_t)ra << 9) + k0 + sc8);
        *(uint4*)&Bh[srow][sc8] = *(const uint4*)(XbH + ((size_t)rb << 9) + k0 + sc8);
        *(uint4*)&Bl[srow][sc8] = *(const uint4*)(XbL + ((size_t)rb << 9) + k0 + sc8);
        __syncthreads();
        short8 ah0 = *(const short8*)&Ah[wr + l15][quad << 3];
        short8 ah1 = *(const short8*)&Ah[wr + 16 + l15][quad << 3];
        short8 al0 = *(const short8*)&Al[wr + l15][quad << 3];
        short8 al1 = *(const short8*)&Al[wr + 16 + l15][quad << 3];
        short8 bh0 = *(const short8*)&Bh[wc + l15][quad << 3];
        short8 bh1 = *(const short8*)&Bh[wc + 16 + l15][quad << 3];
        short8 bl0 = *(const short8*)&Bl[wc + l15][quad << 3];
        short8 bl1 = *(const short8*)&Bl[wc + 16 + l15][quad << 3];
        acc[0][0] = __builtin_amdgcn_mfma_f32_16x16x32_bf16(ah0, bh0, acc[0][0], 0, 0, 0);
        acc[0][0] = __builtin_amdgcn_mfma_f32_16x16x32_bf16(ah0, bl0, acc[0][0], 0, 0, 0);
        acc[0][0] = __builtin_amdgcn_mfma_f32_16x16x32_bf16(al0, bh0, acc[0][0], 0, 0, 0);
        acc[0][1] = __builtin_amdgcn_mfma_f32_16x16x32_bf16(ah0, bh1, acc[0][1], 0, 0, 0);
        acc[0][1] = __builtin_amdgcn_mfma_f32_16x16x32_bf16(ah0, bl1, acc[0][1], 0, 0, 0);
        acc[0][1] = __builtin_amdgcn_mfma_f32_16x16x32_bf16(al0, bh1, acc[0][1], 0, 0, 0);
        acc[1][0] = __builtin_amdgcn_mfma_f32_16x16x32_bf16(ah1, bh0, acc[1][0], 0, 0, 0);
        acc[1][0] = __builtin_amdgcn_mfma_f32_16x16x32_bf16(ah1, bl0, acc[1][0], 0, 0, 0);
        acc[1][0] = __builtin_amdgcn_mfma_f32_16x16x32_bf16(al1, bh0, acc[1][0], 0, 0, 0);
        acc[1][1] = __builtin_amdgcn_mfma_f32_16x16x32_bf16(ah1, bh1, acc[1][1], 0, 0, 0);
        acc[1][1] = __builtin_amdgcn_mfma_f32_16x16x32_bf16(ah1, bl1, acc[1][1], 0, 0, 0);
        acc[1][1] = __builtin_amdgcn_mfma_f32_16x16x32_bf16(al1, bh1, acc[1][1], 0, 0, 0);
        __syncthreads();
    }
    #pragma unroll
    for (int mi = 0; mi < 2; mi++){
        #pragma unroll
        for (int r = 0; r < 4; r++){
            int row = gm + wr + (mi << 4) + (quad << 2) + r;
            if (row < n){
                #pragma unroll
                for (int ni = 0; ni < 2; ni++){
                    int col = gn + wc + (ni << 4) + l15;
                    if (col < n) Cb[(size_t)row * n + col] = acc[mi][ni][r];
                }
            }
        }
    }
}

// ---------------- concat conv pyramids
__global__ __launch_bounds__(256)
void pcat_copy(const float* __restrict__ C1, const float* __restrict__ C2,
               const float* __restrict__ C3, float* __restrict__ PC){
    int idx = blockIdx.x * 256 + threadIdx.x;
    int d = idx & 511;
    int r = (idx >> 9) % 336;
    int b = idx / (336 * 512);
    float v;
    if (r < 256)       v = C1[(((size_t)b * 256 + r) << 9) + d];
    else if (r < 320)  v = C2[(((size_t)b * 64 + (r - 256)) << 9) + d];
    else               v = C3[(((size_t)b * 16 + (r - 320)) << 9) + d];
    PC[idx] = v;
}

__global__ __launch_bounds__(256)
void xenc_copy(const float* __restrict__ xe, float* __restrict__ dst){
    int idx = blockIdx.x * 256 + threadIdx.x;
    int d = idx & 511;
    int l = (idx >> 9) & 1023;
    int b = idx >> 19;
    dst[(((size_t)b * LT + l) << 9) + d] = xe[idx];
}

// ---------------- LayerNorm over 512, wave per row
__global__ __launch_bounds__(256)
void ln_kernel(const float* __restrict__ in, const float* __restrict__ g,
               const float* __restrict__ bta, float* __restrict__ out, float eps){
    int wid = threadIdx.x >> 6, lane = threadIdx.x & 63;
    int row = blockIdx.x * 4 + wid;
    const float* p = in + ((size_t)row << 9);
    float vals[8]; float s = 0.f, s2 = 0.f;
    #pragma unroll
    for (int t = 0; t < 8; t++){
        float v = p[lane + t * 64]; vals[t] = v; s += v; s2 += v * v;
    }
    #pragma unroll
    for (int off = 32; off; off >>= 1){
        s  += __shfl_xor(s,  off, 64);
        s2 += __shfl_xor(s2, off, 64);
    }
    float mu = s * (1.f / 512.f);
    float var = s2 * (1.f / 512.f) - mu * mu;
    float r = rsqrtf(var + eps);
    float* q = out + ((size_t)row << 9);
    #pragma unroll
    for (int t = 0; t < 8; t++){
        int c = lane + t * 64;
        q[c] = (vals[t] - mu) * r * g[c] + bta[c];
    }
}

// ---------------- row L2-normalize → bf16 hi/lo split
__global__ __launch_bounds__(256)
void rownorm_kernel(const float* __restrict__ in, ushort* __restrict__ XHp,
                    ushort* __restrict__ XLp){
    int wid = threadIdx.x >> 6, lane = threadIdx.x & 63;
    int row = blockIdx.x * 4 + wid;
    const float* p = in + ((size_t)row << 9);
    float vals[8]; float s2 = 0.f;
    #pragma unroll
    for (int t = 0; t < 8; t++){
        float v = p[lane + t * 64]; vals[t] = v; s2 += v * v;
    }
    #pragma unroll
    for (int off = 32; off; off >>= 1) s2 += __shfl_xor(s2, off, 64);
    float inv = 1.f / fmaxf(sqrtf(s2), 1e-8f);
    ushort* qh = XHp + ((size_t)row << 9);
    ushort* ql = XLp + ((size_t)row << 9);
    #pragma unroll
    for (int t = 0; t < 8; t++){
        float v = vals[t] * inv;
        ushort h = f2b(v);
        qh[lane + t * 64] = h;
        ql[lane + t * 64] = f2b(v - b2f(h));
    }
}

// ---------------- top-k: wave-per-row register selection, bitmask output
// MB[row][w] words; winner bits accumulated in registers, no atomics, no memset.
__global__ __launch_bounds__(256)
void topk_sel(const float* __restrict__ SIM, u64* __restrict__ MB){
    int wid = threadIdx.x >> 6, lane = threadIdx.x & 63;
    int r = blockIdx.x * 4 + wid;        // 0..B*LT-1
    int b = r / LT, i = r % LT;
    int bi, st, n; blk_info(i, bi, st, n);
    u64* mrow = MB + ((size_t)b * LT + i) * MBW;
    u64 myw = 0;
    if (lane == 21) myw = 0xFFFFFFFFFFFF0000ULL;     // pad: keys 1360..1407 banned
    if (n == 16){                                     // all 16 in-block keys banned
        if (lane == 21) myw = ~0ULL;
        if (lane < MBW) mrow[lane] = myw;
        return;
    }
    int goff = (bi == 0) ? SG0 : (bi == 1) ? SG1 : SG2;
    const float* srow = SIM + (size_t)b * SBT + goff + (size_t)(i - st) * n;
    int ns = n >> 6;
    float vals[16];
    #pragma unroll
    for (int t = 0; t < 16; t++)
        vals[t] = (t < ns) ? srow[lane + (t << 6)] : -FLT_MAX;
    for (int it = 0; it < 32; it++){
        float bv = vals[0]; int bt = 0;
        #pragma unroll
        for (int t = 1; t < 16; t++)
            if (vals[t] > bv){ bv = vals[t]; bt = t; }
        int bidx = (bt << 6) + lane;
        #pragma unroll
        for (int off = 1; off < 64; off <<= 1){
            float ov = __shfl_xor(bv, off, 64);
            int   oi = __shfl_xor(bidx, off, 64);
            if (ov > bv || (ov == bv && oi < bidx)){ bv = ov; bidx = oi; }
        }
        int gb = st + bidx;
        if (lane == (gb >> 6)) myw |= 1ULL << (gb & 63);
        if ((bidx & 63) == lane){
            int bt2 = bidx >> 6;
            #pragma unroll
            for (int t = 0; t < 16; t++) if (t == bt2) vals[t] = -FLT_MAX;
        }
    }
    if (lane < MBW) mrow[lane] = myw;
}

// ---------------- sparse temporal attention (Q pre-scaled, exp2 domain)
__global__ __launch_bounds__(256)
void attn_sparse(const ushort* __restrict__ Q, const ushort* __restrict__ Kp,
                 const ushort* __restrict__ Vt, const int* __restrict__ IDX,
                 const int* __restrict__ CNT, float* __restrict__ O){
    int wid = threadIdx.x >> 6, lane = threadIdx.x & 63;
    int row = blockIdx.x * 4 + wid;
    int b = row / (NHH * LT);
    int rem = row % (NHH * LT);
    int h = rem / LT, i = rem % LT;
    int c = CNT[i];
    int jl = IDX[i * 12 + (lane % 12)];
    float qd = b2f(Q[(((size_t)b * LT + i) << 9) + h * 64 + lane]);
    const ushort* kb = Kp + (((size_t)b * LT) << 9) + h * 64 + lane;
    const ushort* vb = Vt + ((size_t)(b * 512 + h * 64 + lane)) * LT;
    float m = -FLT_MAX, lsum = 0.f, o = 0.f;
    for (int t = 0; t < c; t++){
        int j = __shfl(jl, t, 64);
        float s = qd * b2f(kb[(size_t)j << 9]);
        #pragma unroll
        for (int off = 32; off; off >>= 1) s += __shfl_xor(s, off, 64);
        float mn = fmaxf(m, s);
        float sc = exp2f(m - mn);
        float p  = exp2f(s - mn);
        lsum = lsum * sc + p;
        o = o * sc + p * b2f(vb[j]);
        m = mn;
    }
    O[(((size_t)b * LT + i) << 9) + h * 64 + lane] = o / lsum;
}

// ---------------- MFMA flash attention (semantic, bitmask, no online max)
__global__ __launch_bounds__(256)
void flash_mfma(const ushort* __restrict__ Q, const ushort* __restrict__ Kp,
                const ushort* __restrict__ Vt, const u64* __restrict__ MB,
                float* __restrict__ O)
{
    __shared__ ushort Ks[64][72];
    __shared__ ushort Vs[64][72];
    __shared__ u64 Ms64[64];
    __shared__ ushort Ps[4][16][72];
    int bh = blockIdx.y, b = bh >> 3, h = bh & 7;
    int q0 = blockIdx.x << 6;
    int tid = threadIdx.x;
    int w = tid >> 6, lane = tid & 63, quad = lane >> 4, l15 = lane & 15;

    int qm = q0 + w * 16 + l15;
    int qmc = (qm < LT) ? qm : (LT - 1);
    const ushort* qp = Q + ((size_t)(b * LT + qmc) << 9) + h * 64 + (quad << 3);
    short8 qf0 = *(const short8*)qp;
    short8 qf1 = *(const short8*)(qp + 32);

    float l_acc[4] = {0.f, 0.f, 0.f, 0.f};
    f32x4 Oacc[4];
    #pragma unroll
    for (int dt = 0; dt < 4; dt++) Oacc[dt] = (f32x4){0.f,0.f,0.f,0.f};

    int srow = tid >> 2, sc = (tid & 3) << 4;
    const u64* Mbase = MB + (size_t)b * LT * MBW;

    for (int kt = 0; kt < 22; kt++){
        int k0 = kt << 6;
        __syncthreads();
        {
            int krow = k0 + srow; if (krow >= LT) krow = LT - 1;
            const ushort* kp = Kp + ((size_t)(b * LT + krow) << 9) + h * 64 + sc;
            *(uint4*)&Ks[srow][sc]     = *(const uint4*)kp;
            *(uint4*)&Ks[srow][sc + 8] = *(const uint4*)(kp + 8);
            int kbase = k0 + sc; if (kbase > LT - 16) kbase = LT - 16;
            const ushort* vp = Vt + ((size_t)(b * 512 + h * 64 + srow)) * LT + kbase;
            *(uint4*)&Vs[srow][sc]     = *(const uint4*)vp;
            *(uint4*)&Vs[srow][sc + 8] = *(const uint4*)(vp + 8);
            if (tid < 64){
                int mrow = q0 + tid; if (mrow >= LT) mrow = LT - 1;
                Ms64[tid] = Mbase[(size_t)mrow * MBW + kt];
            }
        }
        __syncthreads();
        f32x4 s[4];
        #pragma unroll
        for (int nt = 0; nt < 4; nt++) s[nt] = (f32x4){0.f,0.f,0.f,0.f};
        #pragma unroll
        for (int nt = 0; nt < 4; nt++){
            short8 kf0 = *(const short8*)&Ks[(nt << 4) + l15][quad << 3];
            short8 kf1 = *(const short8*)&Ks[(nt << 4) + l15][32 + (quad << 3)];
            s[nt] = __builtin_amdgcn_mfma_f32_16x16x32_bf16(qf0, kf0, s[nt], 0, 0, 0);
            s[nt] = __builtin_amdgcn_mfma_f32_16x16x32_bf16(qf1, kf1, s[nt], 0, 0, 0);
        }
        // p = exp2(s) masked; no max subtraction (scores bounded); l deferred
        #pragma unroll
        for (int r = 0; r < 4; r++){
            int lrow = (w << 4) + (quad << 2) + r;
            u64 bits = Ms64[lrow];
            float psum = 0.f;
            #pragma unroll
            for (int nt = 0; nt < 4; nt++){
                uint32_t bad = (uint32_t)(bits >> (nt * 16 + l15)) & 1u;
                float pv = bad ? 0.f : exp2f(s[nt][r]);
                psum += pv;
                Ps[w][(quad << 2) + r][(nt << 4) + l15] = f2b(pv);
            }
            l_acc[r] += psum;
        }
        short8 pf0 = *(const short8*)&Ps[w][l15][quad << 3];
        short8 pf1 = *(const short8*)&Ps[w][l15][32 + (quad << 3)];
        #pragma unroll
        for (int dt = 0; dt < 4; dt++){
            short8 vf0 = *(const short8*)&Vs[(dt << 4) + l15][quad << 3];
            short8 vf1 = *(const short8*)&Vs[(dt << 4) + l15][32 + (quad << 3)];
            Oacc[dt] = __builtin_amdgcn_mfma_f32_16x16x32_bf16(pf0, vf0, Oacc[dt], 0, 0, 0);
            Oacc[dt] = __builtin_amdgcn_mfma_f32_16x16x32_bf16(pf1, vf1, Oacc[dt], 0, 0, 0);
        }
    }
    #pragma unroll
    for (int r = 0; r < 4; r++){
        #pragma unroll
        for (int off = 1; off < 16; off <<= 1)
            l_acc[r] += __shfl_xor(l_acc[r], off, 64);
    }
    #pragma unroll
    for (int r = 0; r < 4; r++){
        int qrow = q0 + (w << 4) + (quad << 2) + r;
        if (qrow < LT){
            float inv = 1.f / l_acc[r];
            #pragma unroll
            for (int dt = 0; dt < 4; dt++)
                O[((size_t)(b * LT + qrow) << 9) + h * 64 + (dt << 4) + l15] = Oacc[dt][r] * inv;
        }
    }
}

// ---------------- x = (t + s + x)/3
__global__ __launch_bounds__(256)
void add3_kernel(const float* __restrict__ T, const float* __restrict__ S,
                 float* __restrict__ X){
    size_t idx = (size_t)blockIdx.x * 256 + threadIdx.x;
    X[idx] = (T[idx] + S[idx] + X[idx]) * (1.f / 3.f);
}

extern "C" void kernel_launch(void* const* d_in, const int* in_sizes, int n_in,
                              void* d_out, int out_size, void* d_ws, size_t ws_size,
                              hipStream_t stream)
{
    const float* x_enc   = (const float*)d_in[0];
    const float* down_W  = (const float*)d_in[1];
    const float* down_b  = (const float*)d_in[2];
    const float* conv_W  = (const float*)d_in[3];
    const float* conv_b  = (const float*)d_in[4];
    const float* up_W    = (const float*)d_in[5];
    const float* up_b    = (const float*)d_in[6];
    const float* bc_g    = (const float*)d_in[7];
    const float* bc_b    = (const float*)d_in[8];
    const float* aWq     = (const float*)d_in[9];
    const float* aWk     = (const float*)d_in[10];
    const float* aWv     = (const float*)d_in[11];
    const float* afcW    = (const float*)d_in[12];
    const float* afcb    = (const float*)d_in[13];
    const float* alng    = (const float*)d_in[14];
    const float* alnb    = (const float*)d_in[15];
    const float* fW1     = (const float*)d_in[16];
    const float* fb1     = (const float*)d_in[17];
    const float* fW2     = (const float*)d_in[18];
    const float* fb2     = (const float*)d_in[19];
    const float* flng    = (const float*)d_in[20];
    const float* flnb    = (const float*)d_in[21];

    const size_t NBL = (size_t)NBLE;
    float* X   = (float*)d_ws;
    float* TMP = X   + NBL;
    float* Qb  = TMP + NBL;
    float* Kb  = Qb  + NBL;
    float* Vb  = Kb  + NBL;
    float* AO  = Vb  + NBL;
    float* TO  = AO  + NBL;
    float* SO  = TO  + NBL;
    u64* MBm = (u64*)(SO + NBL);                      // B*LT*24 words
    int* TIDX = (int*)(MBm + (size_t)BB * LT * MBW);
    int* TCNT = TIDX + (size_t)LT * 12;
    ushort* WG = (ushort*)(TCNT + LT);
    const size_t M512 = 262144;
    ushort* WdownT = WG;                 size_t wo = M512;
    ushort* WupT   = WG + wo;            wo += M512;
    ushort* Wqkv   = WG + wo;            wo += 12 * M512;   // 4 layers x [Wq|Wk|Wv]^T
    ushort* WfT    = WG + wo;            wo += 4 * M512;
    ushort* W1T    = WG + wo;            wo += 2 * M512;
    ushort* W2T    = WG + wo;            wo += 2 * M512;
    ushort* WCt    = WG + wo;            wo += 3 * 1048576;
    size_t need = 8 * NBL * sizeof(float) + (size_t)BB * LT * MBW * 8
                + (size_t)LT * 13 * 4 + wo * sizeof(ushort);
    if (ws_size < need) return;

    // aliases (lifetimes disjoint)
    float* Y    = Qb;
    float* C1   = Kb;
    float* C2   = C1 + (size_t)BB*256*512;
    float* C3   = C2 + (size_t)BB*64*512;
    float* PCAT = Vb;
    ushort* XNh = (ushort*)AO;            // hi/lo bf16 normalized rows (2*NBL ushorts = AO)
    ushort* XNl = XNh + NBL;
    float* SIMB = Qb;
    float* Hf   = Qb;
    ushort* QbH = (ushort*)Qb;
    ushort* KbH = (ushort*)Kb;
    ushort* VtH = (ushort*)Vb;

    auto gemmB = [&](const float* A, const ushort* Bw, const float* bias,
                     const float* res, void* C, int M, int N, int K,
                     int act, int omode, int mpb, int orpb, int ooff){
        dim3 grid(N / 128, M / 64);
        gemm_bf16<<<grid, 256, 0, stream>>>(A, Bw, bias, res, C, M, N, K,
                                            act, omode, mpb, orpb, ooff);
    };

    build_tidx<<<(LT + 255) / 256, 256, 0, stream>>>(TIDX, TCNT);
    wtrans<<<dim3(8, 8, 1), 256, 0, stream>>>(down_W, WdownT, 512, 512, M512);
    wtrans<<<dim3(8, 8, 1), 256, 0, stream>>>(up_W,   WupT,   512, 512, M512);
    wtrans<<<dim3(8, 8, 4), 256, 0, stream>>>(aWq,  Wqkv + 0 * M512, 512, 512, 3 * (long)M512);
    wtrans<<<dim3(8, 8, 4), 256, 0, stream>>>(aWk,  Wqkv + 1 * M512, 512, 512, 3 * (long)M512);
    wtrans<<<dim3(8, 8, 4), 256, 0, stream>>>(aWv,  Wqkv + 2 * M512, 512, 512, 3 * (long)M512);
    wtrans<<<dim3(8, 8, 4), 256, 0, stream>>>(afcW, WfT, 512, 512, M512);
    wtrans<<<dim3(8, 8, 2), 256, 0, stream>>>(fW1,  W1T, 512, 512, M512);
    wtrans<<<dim3(8, 8, 2), 256, 0, stream>>>(fW2,  W2T, 512, 512, M512);
    wconv<<<dim3(4096, 3), 256, 0, stream>>>(conv_W, WCt);

    // ---- bottleneck
    gemmB(x_enc, WdownT, down_b, nullptr, Y, BB*1024, 512, 512, 0, 0, 0, 0, 0);
    gemmB(Y,  WCt,             conv_b + 0,    nullptr, C1, BB*256, 512, 2048, 1, 0, 0, 0, 0);
    gemmB(C1, WCt + 1048576,   conv_b + 512,  nullptr, C2, BB*64,  512, 2048, 1, 0, 0, 0, 0);
    gemmB(C2, WCt + 2*1048576, conv_b + 1024, nullptr, C3, BB*16,  512, 2048, 1, 0, 0, 0, 0);
    pcat_copy<<<(BB*336*512)/256, 256, 0, stream>>>(C1, C2, C3, PCAT);
    gemmB(PCAT, WupT, up_b, nullptr, TMP, BB*336, 512, 512, 0, 0, 336, LT, 1024);
    xenc_copy<<<(BB*1024*512)/256, 256, 0, stream>>>(x_enc, TMP);
    ln_kernel<<<(BB*LT)/4, 256, 0, stream>>>(TMP, bc_g, bc_b, X, 1e-5f);

    // ---- transformer layers
    for (int l = 0; l < 2; l++){
        rownorm_kernel<<<(BB*LT)/4, 256, 0, stream>>>(X, XNh, XNl);
        sim_mfma<<<dim3(274, BB), 256, 0, stream>>>(XNh, XNl, SIMB);
        topk_sel<<<(BB*LT)/4, 256, 0, stream>>>(SIMB, MBm);

        for (int j = 0; j < 2; j++){
            int li = l * 2 + j;
            const float* bf = afcb + (size_t)li * 512;
            const float* lg = alng + (size_t)li * 512;
            const float* lb = alnb + (size_t)li * 512;
            // fused QKV projection: writes Q(scaled)->QbH, K->KbH, V^T->VtH
            gemmB(X, Wqkv + (size_t)li * 3 * M512, nullptr, nullptr, QbH,
                  BB*LT, 1536, 512, 0, 3, 0, 0, 0);
            if (j == 0)
                attn_sparse<<<(BB*NHH*LT)/4, 256, 0, stream>>>(QbH, KbH, VtH, TIDX, TCNT, AO);
            else
                flash_mfma<<<dim3(22, 32), 256, 0, stream>>>(QbH, KbH, VtH, MBm, AO);
            gemmB(AO, WfT + (size_t)li * M512, bf, X, TMP, BB*LT, 512, 512, 0, 0, 0, 0, 0);
            ln_kernel<<<(BB*LT)/4, 256, 0, stream>>>(TMP, lg, lb, (j == 0) ? TO : SO, 1e-6f);
        }
        add3_kernel<<<(int)(NBL/256), 256, 0, stream>>>(TO, SO, X);

        // FFN
        gemmB(X,  W1T + (size_t)l * M512, fb1 + (size_t)l*512, nullptr, Hf, BB*LT, 512, 512, 2, 0, 0, 0, 0);
        gemmB(Hf, W2T + (size_t)l * M512, fb2 + (size_t)l*512, X, TMP, BB*LT, 512, 512, 0, 0, 0, 0, 0);
        ln_kernel<<<(BB*LT)/4, 256, 0, stream>>>(TMP, flng + (size_t)l*512, flnb + (size_t)l*512,
                                                 (l == 1) ? (float*)d_out : X, 1e-6f);
    }
}

// Round 9
// 1083.652 us; speedup vs baseline: 1.1393x; 1.1393x over previous
//
#include <hip/hip_runtime.h>
#include <float.h>
#include <math.h>
#include <stdint.h>

#define LT 1360
#define BB 4
#define DM 512
#define NHH 8
#define NBLE 2785280   // BB*LT*512 elements
#define MBW 24         // mask words (uint64) per row
#define QSCALE 0.18033688f   // 0.125 * log2(e)

typedef __attribute__((ext_vector_type(8))) short short8;
typedef __attribute__((ext_vector_type(4))) float f32x4;
typedef unsigned long long u64;

__device__ __forceinline__ ushort f2b(float x){
    uint32_t u = __float_as_uint(x);
    return (ushort)((u + 0x7fffu + ((u >> 16) & 1u)) >> 16);
}
__device__ __forceinline__ float b2f(ushort u){
    return __uint_as_float(((uint32_t)u) << 16);
}

// semantic sim buffer layout (per batch)
#define SG0 0
#define SG1 1048576
#define SG2 (SG1 + 65536)
#define SG3 (SG2 + 4096)
#define SBT (SG3 + 256)

__device__ __forceinline__ void blk_info(int i, int& bi, int& st, int& n){
    if (i < 1024){ bi = 0; st = 0;    n = 1024; }
    else if (i < 1280){ bi = 1; st = 1024; n = 256; }
    else if (i < 1344){ bi = 2; st = 1280; n = 64; }
    else { bi = 3; st = 1344; n = 16; }
}

// ---------------- temporal allowed-index lists
__global__ __launch_bounds__(256)
void build_tidx(int* __restrict__ idx, int* __restrict__ cnt){
    int i = blockIdx.x * 256 + threadIdx.x;
    if (i >= LT) return;
    int bi, st, n; blk_info(i, bi, st, n);
    int c = 0; int* row = idx + i * 12;
    int lo = (i - 2 > st) ? i - 2 : st;
    int hi = (i + 2 < st + n - 1) ? i + 2 : st + n - 1;
    for (int j = lo; j <= hi; j++) row[c++] = j;
    if (bi < 3) row[c++] = st + n + (i - st) / 4;
    if (bi > 0){
        int stc = st - n * 4;
        int base = stc + (i - st) * 4;
        for (int t = 0; t < 4; t++) row[c++] = base + t;
    }
    cnt[i] = c;
}

// ---------------- weight transpose+cast: Wd[n*K+k] = bf16(Ws[k*N+n])
__global__ __launch_bounds__(256)
void wtrans(const float* __restrict__ W, ushort* __restrict__ Wt, int K, int N, long dstStride){
    int mat = blockIdx.z;
    const float* Ws = W + (size_t)mat * K * N;
    ushort* Wd = Wt + (size_t)mat * dstStride;
    int k0 = blockIdx.y << 6, n0 = blockIdx.x << 6;
    __shared__ ushort t[64][72];
    int tid = threadIdx.x;
    #pragma unroll
    for (int p = 0; p < 4; p++){
        int idx = tid + (p << 8);
        int r = idx >> 4, c4 = (idx & 15) << 2;
        float4 v = *(const float4*)(Ws + (size_t)(k0 + r) * N + n0 + c4);
        t[c4+0][r] = f2b(v.x); t[c4+1][r] = f2b(v.y);
        t[c4+2][r] = f2b(v.z); t[c4+3][r] = f2b(v.w);
    }
    __syncthreads();
    #pragma unroll
    for (int p = 0; p < 4; p++){
        int idx = tid + (p << 8);
        int r = idx >> 4, c4 = (idx & 15) << 2;
        *(uint2*)&Wd[(size_t)(n0 + r) * K + k0 + c4] = *(uint2*)&t[r][c4];
    }
}

// ---------------- conv weight repack+cast
__global__ __launch_bounds__(256)
void wconv(const float* __restrict__ cw, ushort* __restrict__ wt){
    int conv = blockIdx.y;
    const float* src = cw + (size_t)conv * 512 * 512 * 4;
    ushort* dst = wt + (size_t)conv * 2048 * 512;
    int idx = blockIdx.x * 256 + threadIdx.x;
    int o = idx >> 11, rest = idx & 2047;
    int k = rest >> 9, ii = rest & 511;
    dst[idx] = f2b(src[((size_t)(o << 9) + ii) * 4 + k]);
}

// ---------------- bf16 MFMA GEMM, 64x128 tile, BK=32, 256 thr / 4 waves
// act: 0 none, 2 relu
// omode: 0 f32 out (+row remap), 1 bf16 out, 2 bf16 V^T out, 3 fused QKV out (N=1536, Q scaled)
__global__ __launch_bounds__(256)
void gemm_bf16(const float* __restrict__ A, const ushort* __restrict__ Bw,
               const float* __restrict__ bias, const float* __restrict__ Rres,
               void* __restrict__ Cout, int M, int N, int K,
               int act, int omode, int mpb, int orpb, int ooff)
{
    __shared__ ushort As[64][40];
    __shared__ ushort Bs[128][40];
    int tid = threadIdx.x;
    int lane = tid & 63, w = tid >> 6, quad = lane >> 4, l15 = lane & 15;
    int gm = blockIdx.y << 6, gn = blockIdx.x << 7;
    int arow = tid >> 2, ac8 = (tid & 3) << 3;
    int brow = tid >> 1, bc16 = (tid & 1) << 4;
    f32x4 acc[4][2];
    #pragma unroll
    for (int mi = 0; mi < 4; mi++)
        #pragma unroll
        for (int ni = 0; ni < 2; ni++)
            acc[mi][ni] = (f32x4){0.f,0.f,0.f,0.f};
    const float* Ap = A + (size_t)(gm + arow) * K;
    const ushort* Bp = Bw + (size_t)(gn + brow) * K;
    for (int k0 = 0; k0 < K; k0 += 32){
        float4 a0 = *(const float4*)(Ap + k0 + ac8);
        float4 a1 = *(const float4*)(Ap + k0 + ac8 + 4);
        uint4 av;
        av.x = (uint32_t)f2b(a0.x) | ((uint32_t)f2b(a0.y) << 16);
        av.y = (uint32_t)f2b(a0.z) | ((uint32_t)f2b(a0.w) << 16);
        av.z = (uint32_t)f2b(a1.x) | ((uint32_t)f2b(a1.y) << 16);
        av.w = (uint32_t)f2b(a1.z) | ((uint32_t)f2b(a1.w) << 16);
        *(uint4*)&As[arow][ac8] = av;
        *(uint4*)&Bs[brow][bc16]     = *(const uint4*)(Bp + k0 + bc16);
        *(uint4*)&Bs[brow][bc16 + 8] = *(const uint4*)(Bp + k0 + bc16 + 8);
        __syncthreads();
        short8 af[4], bf[2];
        #pragma unroll
        for (int mi = 0; mi < 4; mi++) af[mi] = *(const short8*)&As[(mi << 4) + l15][quad << 3];
        #pragma unroll
        for (int ni = 0; ni < 2; ni++) bf[ni] = *(const short8*)&Bs[(w << 5) + (ni << 4) + l15][quad << 3];
        #pragma unroll
        for (int mi = 0; mi < 4; mi++)
            #pragma unroll
            for (int ni = 0; ni < 2; ni++)
                acc[mi][ni] = __builtin_amdgcn_mfma_f32_16x16x32_bf16(af[mi], bf[ni], acc[mi][ni], 0, 0, 0);
        __syncthreads();
    }
    #pragma unroll
    for (int mi = 0; mi < 4; mi++){
        #pragma unroll
        for (int r = 0; r < 4; r++){
            int row = gm + (mi << 4) + (quad << 2) + r;
            #pragma unroll
            for (int ni = 0; ni < 2; ni++){
                int col = gn + (w << 5) + (ni << 4) + l15;
                float v = acc[mi][ni][r];
                if (bias) v += bias[col];
                if (Rres) v += Rres[(size_t)row * N + col];
                if (act == 2){ v = fmaxf(v, 0.f); }
                if (omode == 0){
                    int orow = mpb ? (row / mpb) * orpb + ooff + (row % mpb) : row;
                    ((float*)Cout)[(size_t)orow * N + col] = v;
                } else if (omode == 1){
                    ((ushort*)Cout)[(size_t)row * N + col] = f2b(v);
                } else if (omode == 2){
                    int bb = row / LT, ii = row - bb * LT;
                    ((ushort*)Cout)[((size_t)(bb * 512 + col)) * LT + ii] = f2b(v);
                } else {
                    int seg = col >> 9, c5 = col & 511;
                    ushort* Ob = (ushort*)Cout;
                    if (seg == 0)      Ob[(size_t)row * 512 + c5] = f2b(v * QSCALE);
                    else if (seg == 1) Ob[(size_t)2*NBLE + (size_t)row * 512 + c5] = f2b(v);
                    else {
                        int bb = row / LT, ii = row - bb * LT;
                        Ob[(size_t)4*NBLE + ((size_t)(bb * 512 + c5)) * LT + ii] = f2b(v);
                    }
                }
            }
        }
    }
}

// ---------------- split-K bf16 GEMM for tiny-M conv chain: 64x64 tile, fp32 partials
// grid (N/64, M/64, S); each z handles kslice of K. P[z][M][N].
__global__ __launch_bounds__(256)
void gemm_sk(const float* __restrict__ A, const ushort* __restrict__ Bw,
             float* __restrict__ P, int M, int N, int K, int kslice)
{
    __shared__ ushort As[64][40];
    __shared__ ushort Bs[64][40];
    int tid = threadIdx.x;
    int lane = tid & 63, w = tid >> 6, quad = lane >> 4, l15 = lane & 15;
    int gm = blockIdx.y << 6, gn = blockIdx.x << 6;
    int wr = (w >> 1) << 5, wc = (w & 1) << 5;
    int srow = tid >> 2, sc8 = (tid & 3) << 3;
    int ks = blockIdx.z * kslice;
    f32x4 acc[2][2];
    #pragma unroll
    for (int mi = 0; mi < 2; mi++)
        #pragma unroll
        for (int ni = 0; ni < 2; ni++)
            acc[mi][ni] = (f32x4){0.f,0.f,0.f,0.f};
    const float* Ap = A + (size_t)(gm + srow) * K;
    const ushort* Bp = Bw + (size_t)(gn + srow) * K;
    for (int k0 = ks; k0 < ks + kslice; k0 += 32){
        float4 a0 = *(const float4*)(Ap + k0 + sc8);
        float4 a1 = *(const float4*)(Ap + k0 + sc8 + 4);
        uint4 av;
        av.x = (uint32_t)f2b(a0.x) | ((uint32_t)f2b(a0.y) << 16);
        av.y = (uint32_t)f2b(a0.z) | ((uint32_t)f2b(a0.w) << 16);
        av.z = (uint32_t)f2b(a1.x) | ((uint32_t)f2b(a1.y) << 16);
        av.w = (uint32_t)f2b(a1.z) | ((uint32_t)f2b(a1.w) << 16);
        *(uint4*)&As[srow][sc8] = av;
        *(uint4*)&Bs[srow][sc8] = *(const uint4*)(Bp + k0 + sc8);
        __syncthreads();
        short8 af0 = *(const short8*)&As[wr + l15][quad << 3];
        short8 af1 = *(const short8*)&As[wr + 16 + l15][quad << 3];
        short8 bf0 = *(const short8*)&Bs[wc + l15][quad << 3];
        short8 bf1 = *(const short8*)&Bs[wc + 16 + l15][quad << 3];
        acc[0][0] = __builtin_amdgcn_mfma_f32_16x16x32_bf16(af0, bf0, acc[0][0], 0, 0, 0);
        acc[0][1] = __builtin_amdgcn_mfma_f32_16x16x32_bf16(af0, bf1, acc[0][1], 0, 0, 0);
        acc[1][0] = __builtin_amdgcn_mfma_f32_16x16x32_bf16(af1, bf0, acc[1][0], 0, 0, 0);
        acc[1][1] = __builtin_amdgcn_mfma_f32_16x16x32_bf16(af1, bf1, acc[1][1], 0, 0, 0);
        __syncthreads();
    }
    float* Pz = P + (size_t)blockIdx.z * M * N;
    #pragma unroll
    for (int mi = 0; mi < 2; mi++){
        #pragma unroll
        for (int r = 0; r < 4; r++){
            int row = gm + wr + (mi << 4) + (quad << 2) + r;
            #pragma unroll
            for (int ni = 0; ni < 2; ni++){
                int col = gn + wc + (ni << 4) + l15;
                Pz[(size_t)row * N + col] = acc[mi][ni][r];
            }
        }
    }
}

// ---------------- split-K reduce + bias + scaled ELU (conv epilogue)
__global__ __launch_bounds__(256)
void sk_reduce(const float* __restrict__ P, const float* __restrict__ bias,
               float* __restrict__ C, int MN, int S)
{
    int idx = (blockIdx.x * 256 + threadIdx.x) << 2;
    if (idx >= MN) return;
    float4 s = {0.f, 0.f, 0.f, 0.f};
    for (int z = 0; z < S; z++){
        float4 v = *(const float4*)(P + (size_t)z * MN + idx);
        s.x += v.x; s.y += v.y; s.z += v.z; s.w += v.w;
    }
    const float cscale = 0.9999950000375f;
    int col = idx & 511;
    float o[4] = {s.x, s.y, s.z, s.w};
    #pragma unroll
    for (int t = 0; t < 4; t++){
        float v = (o[t] + bias[col + t]) * cscale;
        o[t] = (v > 0.f) ? v : expm1f(v);
    }
    *(float4*)(C + idx) = (float4){o[0], o[1], o[2], o[3]};
}

// ---------------- semantic sim via split-bf16 MFMA (hi/lo precomputed)
__global__ __launch_bounds__(256)
void sim_mfma(const ushort* __restrict__ XH, const ushort* __restrict__ XL,
              float* __restrict__ SIM){
    __shared__ ushort Ah[64][40], Al[64][40], Bh[64][40], Bl[64][40];
    int x = blockIdx.x, b = blockIdx.y;
    int ti, tj, st, n, goff;
    if (x < 256){ ti = x >> 4; tj = x & 15; st = 0; n = 1024; goff = SG0; }
    else if (x < 272){ int y = x - 256; ti = y >> 2; tj = y & 3; st = 1024; n = 256; goff = SG1; }
    else if (x == 272){ ti = 0; tj = 0; st = 1280; n = 64; goff = SG2; }
    else { ti = 0; tj = 0; st = 1344; n = 16; goff = SG3; }
    const ushort* XbH = XH + (((size_t)b * LT + st) << 9);
    const ushort* XbL = XL + (((size_t)b * LT + st) << 9);
    float* Cb = SIM + (size_t)b * SBT + goff;
    int gm = ti << 6, gn = tj << 6;
    int tid = threadIdx.x;
    int lane = tid & 63, w = tid >> 6, quad = lane >> 4, l15 = lane & 15;
    int wr = (w >> 1) << 5, wc = (w & 1) << 5;
    int srow = tid >> 2, sc8 = (tid & 3) << 3;
    int ra = gm + srow; if (ra > n - 1) ra = n - 1;
    int rb = gn + srow; if (rb > n - 1) rb = n - 1;
    f32x4 acc[2][2];
    #pragma unroll
    for (int mi = 0; mi < 2; mi++)
        #pragma unroll
        for (int ni = 0; ni < 2; ni++)
            acc[mi][ni] = (f32x4){0.f,0.f,0.f,0.f};
    for (int k0 = 0; k0 < 512; k0 += 32){
        *(uint4*)&Ah[srow][sc8] = *(const uint4*)(XbH + ((size_t)ra << 9) + k0 + sc8);
        *(uint4*)&Al[srow][sc8] = *(const uint4*)(XbL + ((size_t)ra << 9) + k0 + sc8);
        *(uint4*)&Bh[srow][sc8] = *(const uint4*)(XbH + ((size_t)rb << 9) + k0 + sc8);
        *(uint4*)&Bl[srow][sc8] = *(const uint4*)(XbL + ((size_t)rb << 9) + k0 + sc8);
        __syncthreads();
        short8 ah0 = *(const short8*)&Ah[wr + l15][quad << 3];
        short8 ah1 = *(const short8*)&Ah[wr + 16 + l15][quad << 3];
        short8 al0 = *(const short8*)&Al[wr + l15][quad << 3];
        short8 al1 = *(const short8*)&Al[wr + 16 + l15][quad << 3];
        short8 bh0 = *(const short8*)&Bh[wc + l15][quad << 3];
        short8 bh1 = *(const short8*)&Bh[wc + 16 + l15][quad << 3];
        short8 bl0 = *(const short8*)&Bl[wc + l15][quad << 3];
        short8 bl1 = *(const short8*)&Bl[wc + 16 + l15][quad << 3];
        acc[0][0] = __builtin_amdgcn_mfma_f32_16x16x32_bf16(ah0, bh0, acc[0][0], 0, 0, 0);
        acc[0][0] = __builtin_amdgcn_mfma_f32_16x16x32_bf16(ah0, bl0, acc[0][0], 0, 0, 0);
        acc[0][0] = __builtin_amdgcn_mfma_f32_16x16x32_bf16(al0, bh0, acc[0][0], 0, 0, 0);
        acc[0][1] = __builtin_amdgcn_mfma_f32_16x16x32_bf16(ah0, bh1, acc[0][1], 0, 0, 0);
        acc[0][1] = __builtin_amdgcn_mfma_f32_16x16x32_bf16(ah0, bl1, acc[0][1], 0, 0, 0);
        acc[0][1] = __builtin_amdgcn_mfma_f32_16x16x32_bf16(al0, bh1, acc[0][1], 0, 0, 0);
        acc[1][0] = __builtin_amdgcn_mfma_f32_16x16x32_bf16(ah1, bh0, acc[1][0], 0, 0, 0);
        acc[1][0] = __builtin_amdgcn_mfma_f32_16x16x32_bf16(ah1, bl0, acc[1][0], 0, 0, 0);
        acc[1][0] = __builtin_amdgcn_mfma_f32_16x16x32_bf16(al1, bh0, acc[1][0], 0, 0, 0);
        acc[1][1] = __builtin_amdgcn_mfma_f32_16x16x32_bf16(ah1, bh1, acc[1][1], 0, 0, 0);
        acc[1][1] = __builtin_amdgcn_mfma_f32_16x16x32_bf16(ah1, bl1, acc[1][1], 0, 0, 0);
        acc[1][1] = __builtin_amdgcn_mfma_f32_16x16x32_bf16(al1, bh1, acc[1][1], 0, 0, 0);
        __syncthreads();
    }
    #pragma unroll
    for (int mi = 0; mi < 2; mi++){
        #pragma unroll
        for (int r = 0; r < 4; r++){
            int row = gm + wr + (mi << 4) + (quad << 2) + r;
            if (row < n){
                #pragma unroll
                for (int ni = 0; ni < 2; ni++){
                    int col = gn + wc + (ni << 4) + l15;
                    if (col < n) Cb[(size_t)row * n + col] = acc[mi][ni][r];
                }
            }
        }
    }
}

// ---------------- concat conv pyramids
__global__ __launch_bounds__(256)
void pcat_copy(const float* __restrict__ C1, const float* __restrict__ C2,
               const float* __restrict__ C3, float* __restrict__ PC){
    int idx = blockIdx.x * 256 + threadIdx.x;
    int d = idx & 511;
    int r = (idx >> 9) % 336;
    int b = idx / (336 * 512);
    float v;
    if (r < 256)       v = C1[(((size_t)b * 256 + r) << 9) + d];
    else if (r < 320)  v = C2[(((size_t)b * 64 + (r - 256)) << 9) + d];
    else               v = C3[(((size_t)b * 16 + (r - 320)) << 9) + d];
    PC[idx] = v;
}

__global__ __launch_bounds__(256)
void xenc_copy(const float* __restrict__ xe, float* __restrict__ dst){
    int idx = blockIdx.x * 256 + threadIdx.x;
    int d = idx & 511;
    int l = (idx >> 9) & 1023;
    int b = idx >> 19;
    dst[(((size_t)b * LT + l) << 9) + d] = xe[idx];
}

// ---------------- LayerNorm over 512, wave per row
__global__ __launch_bounds__(256)
void ln_kernel(const float* __restrict__ in, const float* __restrict__ g,
               const float* __restrict__ bta, float* __restrict__ out, float eps){
    int wid = threadIdx.x >> 6, lane = threadIdx.x & 63;
    int row = blockIdx.x * 4 + wid;
    const float* p = in + ((size_t)row << 9);
    float vals[8]; float s = 0.f, s2 = 0.f;
    #pragma unroll
    for (int t = 0; t < 8; t++){
        float v = p[lane + t * 64]; vals[t] = v; s += v; s2 += v * v;
    }
    #pragma unroll
    for (int off = 32; off; off >>= 1){
        s  += __shfl_xor(s,  off, 64);
        s2 += __shfl_xor(s2, off, 64);
    }
    float mu = s * (1.f / 512.f);
    float var = s2 * (1.f / 512.f) - mu * mu;
    float r = rsqrtf(var + eps);
    float* q = out + ((size_t)row << 9);
    #pragma unroll
    for (int t = 0; t < 8; t++){
        int c = lane + t * 64;
        q[c] = (vals[t] - mu) * r * g[c] + bta[c];
    }
}

// ---------------- row L2-normalize → bf16 hi/lo split
__global__ __launch_bounds__(256)
void rownorm_kernel(const float* __restrict__ in, ushort* __restrict__ XHp,
                    ushort* __restrict__ XLp){
    int wid = threadIdx.x >> 6, lane = threadIdx.x & 63;
    int row = blockIdx.x * 4 + wid;
    const float* p = in + ((size_t)row << 9);
    float vals[8]; float s2 = 0.f;
    #pragma unroll
    for (int t = 0; t < 8; t++){
        float v = p[lane + t * 64]; vals[t] = v; s2 += v * v;
    }
    #pragma unroll
    for (int off = 32; off; off >>= 1) s2 += __shfl_xor(s2, off, 64);
    float inv = 1.f / fmaxf(sqrtf(s2), 1e-8f);
    ushort* qh = XHp + ((size_t)row << 9);
    ushort* ql = XLp + ((size_t)row << 9);
    #pragma unroll
    for (int t = 0; t < 8; t++){
        float v = vals[t] * inv;
        ushort h = f2b(v);
        qh[lane + t * 64] = h;
        ql[lane + t * 64] = f2b(v - b2f(h));
    }
}

// ---------------- top-k: wave-per-row register selection, bitmask output
__global__ __launch_bounds__(256)
void topk_sel(const float* __restrict__ SIM, u64* __restrict__ MB){
    int wid = threadIdx.x >> 6, lane = threadIdx.x & 63;
    int r = blockIdx.x * 4 + wid;        // 0..B*LT-1
    int b = r / LT, i = r % LT;
    int bi, st, n; blk_info(i, bi, st, n);
    u64* mrow = MB + ((size_t)b * LT + i) * MBW;
    u64 myw = 0;
    if (lane == 21) myw = 0xFFFFFFFFFFFF0000ULL;     // pad: keys 1360..1407 banned
    if (n == 16){                                     // all 16 in-block keys banned
        if (lane == 21) myw = ~0ULL;
        if (lane < MBW) mrow[lane] = myw;
        return;
    }
    int goff = (bi == 0) ? SG0 : (bi == 1) ? SG1 : SG2;
    const float* srow = SIM + (size_t)b * SBT + goff + (size_t)(i - st) * n;
    int ns = n >> 6;
    float vals[16];
    #pragma unroll
    for (int t = 0; t < 16; t++)
        vals[t] = (t < ns) ? srow[lane + (t << 6)] : -FLT_MAX;
    for (int it = 0; it < 32; it++){
        float bv = vals[0]; int bt = 0;
        #pragma unroll
        for (int t = 1; t < 16; t++)
            if (vals[t] > bv){ bv = vals[t]; bt = t; }
        int bidx = (bt << 6) + lane;
        #pragma unroll
        for (int off = 1; off < 64; off <<= 1){
            float ov = __shfl_xor(bv, off, 64);
            int   oi = __shfl_xor(bidx, off, 64);
            if (ov > bv || (ov == bv && oi < bidx)){ bv = ov; bidx = oi; }
        }
        int gb = st + bidx;
        if (lane == (gb >> 6)) myw |= 1ULL << (gb & 63);
        if ((bidx & 63) == lane){
            int bt2 = bidx >> 6;
            #pragma unroll
            for (int t = 0; t < 16; t++) if (t == bt2) vals[t] = -FLT_MAX;
        }
    }
    if (lane < MBW) mrow[lane] = myw;
}

// ---------------- sparse temporal attention (Q pre-scaled, exp2 domain)
__global__ __launch_bounds__(256)
void attn_sparse(const ushort* __restrict__ Q, const ushort* __restrict__ Kp,
                 const ushort* __restrict__ Vt, const int* __restrict__ IDX,
                 const int* __restrict__ CNT, float* __restrict__ O){
    int wid = threadIdx.x >> 6, lane = threadIdx.x & 63;
    int row = blockIdx.x * 4 + wid;
    int b = row / (NHH * LT);
    int rem = row % (NHH * LT);
    int h = rem / LT, i = rem % LT;
    int c = CNT[i];
    int jl = IDX[i * 12 + (lane % 12)];
    float qd = b2f(Q[(((size_t)b * LT + i) << 9) + h * 64 + lane]);
    const ushort* kb = Kp + (((size_t)b * LT) << 9) + h * 64 + lane;
    const ushort* vb = Vt + ((size_t)(b * 512 + h * 64 + lane)) * LT;
    float m = -FLT_MAX, lsum = 0.f, o = 0.f;
    for (int t = 0; t < c; t++){
        int j = __shfl(jl, t, 64);
        float s = qd * b2f(kb[(size_t)j << 9]);
        #pragma unroll
        for (int off = 32; off; off >>= 1) s += __shfl_xor(s, off, 64);
        float mn = fmaxf(m, s);
        float sc = exp2f(m - mn);
        float p  = exp2f(s - mn);
        lsum = lsum * sc + p;
        o = o * sc + p * b2f(vb[j]);
        m = mn;
    }
    O[(((size_t)b * LT + i) << 9) + h * 64 + lane] = o / lsum;
}

// ---------------- MFMA flash attention (semantic, bitmask, no online max)
__global__ __launch_bounds__(256)
void flash_mfma(const ushort* __restrict__ Q, const ushort* __restrict__ Kp,
                const ushort* __restrict__ Vt, const u64* __restrict__ MB,
                float* __restrict__ O)
{
    __shared__ ushort Ks[64][72];
    __shared__ ushort Vs[64][72];
    __shared__ u64 Ms64[64];
    __shared__ ushort Ps[4][16][72];
    int bh = blockIdx.y, b = bh >> 3, h = bh & 7;
    int q0 = blockIdx.x << 6;
    int tid = threadIdx.x;
    int w = tid >> 6, lane = tid & 63, quad = lane >> 4, l15 = lane & 15;

    int qm = q0 + w * 16 + l15;
    int qmc = (qm < LT) ? qm : (LT - 1);
    const ushort* qp = Q + ((size_t)(b * LT + qmc) << 9) + h * 64 + (quad << 3);
    short8 qf0 = *(const short8*)qp;
    short8 qf1 = *(const short8*)(qp + 32);

    float l_acc[4] = {0.f, 0.f, 0.f, 0.f};
    f32x4 Oacc[4];
    #pragma unroll
    for (int dt = 0; dt < 4; dt++) Oacc[dt] = (f32x4){0.f,0.f,0.f,0.f};

    int srow = tid >> 2, sc = (tid & 3) << 4;
    const u64* Mbase = MB + (size_t)b * LT * MBW;

    for (int kt = 0; kt < 22; kt++){
        int k0 = kt << 6;
        __syncthreads();
        {
            int krow = k0 + srow; if (krow >= LT) krow = LT - 1;
            const ushort* kp = Kp + ((size_t)(b * LT + krow) << 9) + h * 64 + sc;
            *(uint4*)&Ks[srow][sc]     = *(const uint4*)kp;
            *(uint4*)&Ks[srow][sc + 8] = *(const uint4*)(kp + 8);
            int kbase = k0 + sc; if (kbase > LT - 16) kbase = LT - 16;
            const ushort* vp = Vt + ((size_t)(b * 512 + h * 64 + srow)) * LT + kbase;
            *(uint4*)&Vs[srow][sc]     = *(const uint4*)vp;
            *(uint4*)&Vs[srow][sc + 8] = *(const uint4*)(vp + 8);
            if (tid < 64){
                int mrow = q0 + tid; if (mrow >= LT) mrow = LT - 1;
                Ms64[tid] = Mbase[(size_t)mrow * MBW + kt];
            }
        }
        __syncthreads();
        f32x4 s[4];
        #pragma unroll
        for (int nt = 0; nt < 4; nt++) s[nt] = (f32x4){0.f,0.f,0.f,0.f};
        #pragma unroll
        for (int nt = 0; nt < 4; nt++){
            short8 kf0 = *(const short8*)&Ks[(nt << 4) + l15][quad << 3];
            short8 kf1 = *(const short8*)&Ks[(nt << 4) + l15][32 + (quad << 3)];
            s[nt] = __builtin_amdgcn_mfma_f32_16x16x32_bf16(qf0, kf0, s[nt], 0, 0, 0);
            s[nt] = __builtin_amdgcn_mfma_f32_16x16x32_bf16(qf1, kf1, s[nt], 0, 0, 0);
        }
        // p = exp2(s) masked; no max subtraction (scores bounded); l deferred
        #pragma unroll
        for (int r = 0; r < 4; r++){
            int lrow = (w << 4) + (quad << 2) + r;
            u64 bits = Ms64[lrow];
            float psum = 0.f;
            #pragma unroll
            for (int nt = 0; nt < 4; nt++){
                uint32_t bad = (uint32_t)(bits >> (nt * 16 + l15)) & 1u;
                float pv = bad ? 0.f : exp2f(s[nt][r]);
                psum += pv;
                Ps[w][(quad << 2) + r][(nt << 4) + l15] = f2b(pv);
            }
            l_acc[r] += psum;
        }
        short8 pf0 = *(const short8*)&Ps[w][l15][quad << 3];
        short8 pf1 = *(const short8*)&Ps[w][l15][32 + (quad << 3)];
        #pragma unroll
        for (int dt = 0; dt < 4; dt++){
            short8 vf0 = *(const short8*)&Vs[(dt << 4) + l15][quad << 3];
            short8 vf1 = *(const short8*)&Vs[(dt << 4) + l15][32 + (quad << 3)];
            Oacc[dt] = __builtin_amdgcn_mfma_f32_16x16x32_bf16(pf0, vf0, Oacc[dt], 0, 0, 0);
            Oacc[dt] = __builtin_amdgcn_mfma_f32_16x16x32_bf16(pf1, vf1, Oacc[dt], 0, 0, 0);
        }
    }
    #pragma unroll
    for (int r = 0; r < 4; r++){
        #pragma unroll
        for (int off = 1; off < 16; off <<= 1)
            l_acc[r] += __shfl_xor(l_acc[r], off, 64);
    }
    #pragma unroll
    for (int r = 0; r < 4; r++){
        int qrow = q0 + (w << 4) + (quad << 2) + r;
        if (qrow < LT){
            float inv = 1.f / l_acc[r];
            #pragma unroll
            for (int dt = 0; dt < 4; dt++)
                O[((size_t)(b * LT + qrow) << 9) + h * 64 + (dt << 4) + l15] = Oacc[dt][r] * inv;
        }
    }
}

// ---------------- x = (t + s + x)/3
__global__ __launch_bounds__(256)
void add3_kernel(const float* __restrict__ T, const float* __restrict__ S,
                 float* __restrict__ X){
    size_t idx = (size_t)blockIdx.x * 256 + threadIdx.x;
    X[idx] = (T[idx] + S[idx] + X[idx]) * (1.f / 3.f);
}

extern "C" void kernel_launch(void* const* d_in, const int* in_sizes, int n_in,
                              void* d_out, int out_size, void* d_ws, size_t ws_size,
                              hipStream_t stream)
{
    const float* x_enc   = (const float*)d_in[0];
    const float* down_W  = (const float*)d_in[1];
    const float* down_b  = (const float*)d_in[2];
    const float* conv_W  = (const float*)d_in[3];
    const float* conv_b  = (const float*)d_in[4];
    const float* up_W    = (const float*)d_in[5];
    const float* up_b    = (const float*)d_in[6];
    const float* bc_g    = (const float*)d_in[7];
    const float* bc_b    = (const float*)d_in[8];
    const float* aWq     = (const float*)d_in[9];
    const float* aWk     = (const float*)d_in[10];
    const float* aWv     = (const float*)d_in[11];
    const float* afcW    = (const float*)d_in[12];
    const float* afcb    = (const float*)d_in[13];
    const float* alng    = (const float*)d_in[14];
    const float* alnb    = (const float*)d_in[15];
    const float* fW1     = (const float*)d_in[16];
    const float* fb1     = (const float*)d_in[17];
    const float* fW2     = (const float*)d_in[18];
    const float* fb2     = (const float*)d_in[19];
    const float* flng    = (const float*)d_in[20];
    const float* flnb    = (const float*)d_in[21];

    const size_t NBL = (size_t)NBLE;
    float* X   = (float*)d_ws;
    float* TMP = X   + NBL;
    float* Qb  = TMP + NBL;
    float* Kb  = Qb  + NBL;
    float* Vb  = Kb  + NBL;
    float* AO  = Vb  + NBL;
    float* TO  = AO  + NBL;
    float* SO  = TO  + NBL;
    u64* MBm = (u64*)(SO + NBL);                      // B*LT*24 words
    int* TIDX = (int*)(MBm + (size_t)BB * LT * MBW);
    int* TCNT = TIDX + (size_t)LT * 12;
    ushort* WG = (ushort*)(TCNT + LT);
    const size_t M512 = 262144;
    ushort* WdownT = WG;                 size_t wo = M512;
    ushort* WupT   = WG + wo;            wo += M512;
    ushort* Wqkv   = WG + wo;            wo += 12 * M512;   // 4 layers x [Wq|Wk|Wv]^T
    ushort* WfT    = WG + wo;            wo += 4 * M512;
    ushort* W1T    = WG + wo;            wo += 2 * M512;
    ushort* W2T    = WG + wo;            wo += 2 * M512;
    ushort* WCt    = WG + wo;            wo += 3 * 1048576;
    size_t need = 8 * NBL * sizeof(float) + (size_t)BB * LT * MBW * 8
                + (size_t)LT * 13 * 4 + wo * sizeof(ushort);
    if (ws_size < need) return;

    // aliases (lifetimes disjoint)
    float* Y    = Qb;
    float* C1   = Kb;
    float* C2   = C1 + (size_t)BB*256*512;
    float* C3   = C2 + (size_t)BB*64*512;
    float* PCAT = Vb;
    float* SKP  = AO;                     // split-K partials (spans AO+TO, 22 MB; bottleneck only)
    ushort* XNh = (ushort*)AO;            // hi/lo bf16 normalized rows
    ushort* XNl = XNh + NBL;
    float* SIMB = Qb;
    float* Hf   = Qb;
    ushort* QbH = (ushort*)Qb;
    ushort* KbH = (ushort*)Kb;
    ushort* VtH = (ushort*)Vb;

    auto gemmB = [&](const float* A, const ushort* Bw, const float* bias,
                     const float* res, void* C, int M, int N, int K,
                     int act, int omode, int mpb, int orpb, int ooff){
        dim3 grid(N / 128, M / 64);
        gemm_bf16<<<grid, 256, 0, stream>>>(A, Bw, bias, res, C, M, N, K,
                                            act, omode, mpb, orpb, ooff);
    };
    auto convG = [&](const float* A, const ushort* Bw, const float* bias,
                     float* C, int M){
        const int S = 8, K = 2048, N = 512;
        gemm_sk<<<dim3(8, M / 64, S), 256, 0, stream>>>(A, Bw, SKP, M, N, K, K / S);
        sk_reduce<<<(M * N) / 1024, 256, 0, stream>>>(SKP, bias, C, M * N, S);
    };

    build_tidx<<<(LT + 255) / 256, 256, 0, stream>>>(TIDX, TCNT);
    wtrans<<<dim3(8, 8, 1), 256, 0, stream>>>(down_W, WdownT, 512, 512, M512);
    wtrans<<<dim3(8, 8, 1), 256, 0, stream>>>(up_W,   WupT,   512, 512, M512);
    wtrans<<<dim3(8, 8, 4), 256, 0, stream>>>(aWq,  Wqkv + 0 * M512, 512, 512, 3 * (long)M512);
    wtrans<<<dim3(8, 8, 4), 256, 0, stream>>>(aWk,  Wqkv + 1 * M512, 512, 512, 3 * (long)M512);
    wtrans<<<dim3(8, 8, 4), 256, 0, stream>>>(aWv,  Wqkv + 2 * M512, 512, 512, 3 * (long)M512);
    wtrans<<<dim3(8, 8, 4), 256, 0, stream>>>(afcW, WfT, 512, 512, M512);
    wtrans<<<dim3(8, 8, 2), 256, 0, stream>>>(fW1,  W1T, 512, 512, M512);
    wtrans<<<dim3(8, 8, 2), 256, 0, stream>>>(fW2,  W2T, 512, 512, M512);
    wconv<<<dim3(4096, 3), 256, 0, stream>>>(conv_W, WCt);

    // ---- bottleneck (conv chain via split-K: tiny M needs K-parallelism)
    gemmB(x_enc, WdownT, down_b, nullptr, Y, BB*1024, 512, 512, 0, 0, 0, 0, 0);
    convG(Y,  WCt,             conv_b + 0,    C1, BB*256);
    convG(C1, WCt + 1048576,   conv_b + 512,  C2, BB*64);
    convG(C2, WCt + 2*1048576, conv_b + 1024, C3, BB*16);
    pcat_copy<<<(BB*336*512)/256, 256, 0, stream>>>(C1, C2, C3, PCAT);
    gemmB(PCAT, WupT, up_b, nullptr, TMP, BB*336, 512, 512, 0, 0, 336, LT, 1024);
    xenc_copy<<<(BB*1024*512)/256, 256, 0, stream>>>(x_enc, TMP);
    ln_kernel<<<(BB*LT)/4, 256, 0, stream>>>(TMP, bc_g, bc_b, X, 1e-5f);

    // ---- transformer layers
    for (int l = 0; l < 2; l++){
        rownorm_kernel<<<(BB*LT)/4, 256, 0, stream>>>(X, XNh, XNl);
        sim_mfma<<<dim3(274, BB), 256, 0, stream>>>(XNh, XNl, SIMB);
        topk_sel<<<(BB*LT)/4, 256, 0, stream>>>(SIMB, MBm);

        for (int j = 0; j < 2; j++){
            int li = l * 2 + j;
            const float* bf = afcb + (size_t)li * 512;
            const float* lg = alng + (size_t)li * 512;
            const float* lb = alnb + (size_t)li * 512;
            // fused QKV projection: writes Q(scaled)->QbH, K->KbH, V^T->VtH
            gemmB(X, Wqkv + (size_t)li * 3 * M512, nullptr, nullptr, QbH,
                  BB*LT, 1536, 512, 0, 3, 0, 0, 0);
            if (j == 0)
                attn_sparse<<<(BB*NHH*LT)/4, 256, 0, stream>>>(QbH, KbH, VtH, TIDX, TCNT, AO);
            else
                flash_mfma<<<dim3(22, 32), 256, 0, stream>>>(QbH, KbH, VtH, MBm, AO);
            gemmB(AO, WfT + (size_t)li * M512, bf, X, TMP, BB*LT, 512, 512, 0, 0, 0, 0, 0);
            ln_kernel<<<(BB*LT)/4, 256, 0, stream>>>(TMP, lg, lb, (j == 0) ? TO : SO, 1e-6f);
        }
        add3_kernel<<<(int)(NBL/256), 256, 0, stream>>>(TO, SO, X);

        // FFN
        gemmB(X,  W1T + (size_t)l * M512, fb1 + (size_t)l*512, nullptr, Hf, BB*LT, 512, 512, 2, 0, 0, 0, 0);
        gemmB(Hf, W2T + (size_t)l * M512, fb2 + (size_t)l*512, X, TMP, BB*LT, 512, 512, 0, 0, 0, 0, 0);
        ln_kernel<<<(BB*LT)/4, 256, 0, stream>>>(TMP, flng + (size_t)l*512, flnb + (size_t)l*512,
                                                 (l == 1) ? (float*)d_out : X, 1e-6f);
    }
}

// Round 10
// 1031.897 us; speedup vs baseline: 1.1965x; 1.0502x over previous
//
#include <hip/hip_runtime.h>
#include <float.h>
#include <math.h>
#include <stdint.h>

#define LT 1360
#define BB 4
#define DM 512
#define NHH 8
#define NBLE 2785280   // BB*LT*512 elements
#define MBW 24         // mask words (uint64) per row
#define QSCALE 0.18033688f   // 0.125 * log2(e)

typedef __attribute__((ext_vector_type(8))) short short8;
typedef __attribute__((ext_vector_type(4))) float f32x4;
typedef unsigned long long u64;

__device__ __forceinline__ ushort f2b(float x){
    uint32_t u = __float_as_uint(x);
    return (ushort)((u + 0x7fffu + ((u >> 16) & 1u)) >> 16);
}
__device__ __forceinline__ float b2f(ushort u){
    return __uint_as_float(((uint32_t)u) << 16);
}

// semantic sim buffer layout (per batch)
#define SG0 0
#define SG1 1048576
#define SG2 (SG1 + 65536)
#define SG3 (SG2 + 4096)
#define SBT (SG3 + 256)

__device__ __forceinline__ void blk_info(int i, int& bi, int& st, int& n){
    if (i < 1024){ bi = 0; st = 0;    n = 1024; }
    else if (i < 1280){ bi = 1; st = 1024; n = 256; }
    else if (i < 1344){ bi = 2; st = 1280; n = 64; }
    else { bi = 3; st = 1344; n = 16; }
}

// ---------------- temporal allowed-index lists (padded to 12 for speculative loads)
__global__ __launch_bounds__(256)
void build_tidx(int* __restrict__ idx, int* __restrict__ cnt){
    int i = blockIdx.x * 256 + threadIdx.x;
    if (i >= LT) return;
    int bi, st, n; blk_info(i, bi, st, n);
    int c = 0; int* row = idx + i * 12;
    int lo = (i - 2 > st) ? i - 2 : st;
    int hi = (i + 2 < st + n - 1) ? i + 2 : st + n - 1;
    for (int j = lo; j <= hi; j++) row[c++] = j;
    if (bi < 3) row[c++] = st + n + (i - st) / 4;
    if (bi > 0){
        int stc = st - n * 4;
        int base = stc + (i - st) * 4;
        for (int t = 0; t < 4; t++) row[c++] = base + t;
    }
    cnt[i] = c;
    for (int t = c; t < 12; t++) row[t] = 0;   // safe pad
}

// ---------------- weight transpose+cast: Wd[n*K+k] = bf16(Ws[k*N+n])
__global__ __launch_bounds__(256)
void wtrans(const float* __restrict__ W, ushort* __restrict__ Wt, int K, int N, long dstStride){
    int mat = blockIdx.z;
    const float* Ws = W + (size_t)mat * K * N;
    ushort* Wd = Wt + (size_t)mat * dstStride;
    int k0 = blockIdx.y << 6, n0 = blockIdx.x << 6;
    __shared__ ushort t[64][72];
    int tid = threadIdx.x;
    #pragma unroll
    for (int p = 0; p < 4; p++){
        int idx = tid + (p << 8);
        int r = idx >> 4, c4 = (idx & 15) << 2;
        float4 v = *(const float4*)(Ws + (size_t)(k0 + r) * N + n0 + c4);
        t[c4+0][r] = f2b(v.x); t[c4+1][r] = f2b(v.y);
        t[c4+2][r] = f2b(v.z); t[c4+3][r] = f2b(v.w);
    }
    __syncthreads();
    #pragma unroll
    for (int p = 0; p < 4; p++){
        int idx = tid + (p << 8);
        int r = idx >> 4, c4 = (idx & 15) << 2;
        *(uint2*)&Wd[(size_t)(n0 + r) * K + k0 + c4] = *(uint2*)&t[r][c4];
    }
}

// ---------------- conv weight repack+cast
__global__ __launch_bounds__(256)
void wconv(const float* __restrict__ cw, ushort* __restrict__ wt){
    int conv = blockIdx.y;
    const float* src = cw + (size_t)conv * 512 * 512 * 4;
    ushort* dst = wt + (size_t)conv * 2048 * 512;
    int idx = blockIdx.x * 256 + threadIdx.x;
    int o = idx >> 11, rest = idx & 2047;
    int k = rest >> 9, ii = rest & 511;
    dst[idx] = f2b(src[((size_t)(o << 9) + ii) * 4 + k]);
}

// ---------------- bf16 MFMA GEMM, 64x128 tile, BK=32, 256 thr / 4 waves
// act: 0 none, 2 relu
// omode: 0 f32 out (+row remap), 1 bf16 out, 2 bf16 V^T out, 3 fused QKV out (N=1536, Q scaled)
__global__ __launch_bounds__(256)
void gemm_bf16(const float* __restrict__ A, const ushort* __restrict__ Bw,
               const float* __restrict__ bias, const float* __restrict__ Rres,
               void* __restrict__ Cout, int M, int N, int K,
               int act, int omode, int mpb, int orpb, int ooff)
{
    __shared__ ushort As[64][40];
    __shared__ ushort Bs[128][40];
    int tid = threadIdx.x;
    int lane = tid & 63, w = tid >> 6, quad = lane >> 4, l15 = lane & 15;
    int gm = blockIdx.y << 6, gn = blockIdx.x << 7;
    int arow = tid >> 2, ac8 = (tid & 3) << 3;
    int brow = tid >> 1, bc16 = (tid & 1) << 4;
    f32x4 acc[4][2];
    #pragma unroll
    for (int mi = 0; mi < 4; mi++)
        #pragma unroll
        for (int ni = 0; ni < 2; ni++)
            acc[mi][ni] = (f32x4){0.f,0.f,0.f,0.f};
    const float* Ap = A + (size_t)(gm + arow) * K;
    const ushort* Bp = Bw + (size_t)(gn + brow) * K;
    for (int k0 = 0; k0 < K; k0 += 32){
        float4 a0 = *(const float4*)(Ap + k0 + ac8);
        float4 a1 = *(const float4*)(Ap + k0 + ac8 + 4);
        uint4 av;
        av.x = (uint32_t)f2b(a0.x) | ((uint32_t)f2b(a0.y) << 16);
        av.y = (uint32_t)f2b(a0.z) | ((uint32_t)f2b(a0.w) << 16);
        av.z = (uint32_t)f2b(a1.x) | ((uint32_t)f2b(a1.y) << 16);
        av.w = (uint32_t)f2b(a1.z) | ((uint32_t)f2b(a1.w) << 16);
        *(uint4*)&As[arow][ac8] = av;
        *(uint4*)&Bs[brow][bc16]     = *(const uint4*)(Bp + k0 + bc16);
        *(uint4*)&Bs[brow][bc16 + 8] = *(const uint4*)(Bp + k0 + bc16 + 8);
        __syncthreads();
        short8 af[4], bf[2];
        #pragma unroll
        for (int mi = 0; mi < 4; mi++) af[mi] = *(const short8*)&As[(mi << 4) + l15][quad << 3];
        #pragma unroll
        for (int ni = 0; ni < 2; ni++) bf[ni] = *(const short8*)&Bs[(w << 5) + (ni << 4) + l15][quad << 3];
        #pragma unroll
        for (int mi = 0; mi < 4; mi++)
            #pragma unroll
            for (int ni = 0; ni < 2; ni++)
                acc[mi][ni] = __builtin_amdgcn_mfma_f32_16x16x32_bf16(af[mi], bf[ni], acc[mi][ni], 0, 0, 0);
        __syncthreads();
    }
    #pragma unroll
    for (int mi = 0; mi < 4; mi++){
        #pragma unroll
        for (int r = 0; r < 4; r++){
            int row = gm + (mi << 4) + (quad << 2) + r;
            #pragma unroll
            for (int ni = 0; ni < 2; ni++){
                int col = gn + (w << 5) + (ni << 4) + l15;
                float v = acc[mi][ni][r];
                if (bias) v += bias[col];
                if (Rres) v += Rres[(size_t)row * N + col];
                if (act == 2){ v = fmaxf(v, 0.f); }
                if (omode == 0){
                    int orow = mpb ? (row / mpb) * orpb + ooff + (row % mpb) : row;
                    ((float*)Cout)[(size_t)orow * N + col] = v;
                } else if (omode == 1){
                    ((ushort*)Cout)[(size_t)row * N + col] = f2b(v);
                } else if (omode == 2){
                    int bb = row / LT, ii = row - bb * LT;
                    ((ushort*)Cout)[((size_t)(bb * 512 + col)) * LT + ii] = f2b(v);
                } else {
                    int seg = col >> 9, c5 = col & 511;
                    ushort* Ob = (ushort*)Cout;
                    if (seg == 0)      Ob[(size_t)row * 512 + c5] = f2b(v * QSCALE);
                    else if (seg == 1) Ob[(size_t)2*NBLE + (size_t)row * 512 + c5] = f2b(v);
                    else {
                        int bb = row / LT, ii = row - bb * LT;
                        ushort hv = f2b(v);
                        Ob[(size_t)4*NBLE + ((size_t)(bb * 512 + c5)) * LT + ii] = hv;  // V^T (flash)
                        Ob[(size_t)5*NBLE + (size_t)row * 512 + c5] = hv;               // V normal (sparse)
                    }
                }
            }
        }
    }
}

// ---------------- split-K bf16 GEMM for tiny-M conv chain: 64x64 tile, fp32 partials
__global__ __launch_bounds__(256)
void gemm_sk(const float* __restrict__ A, const ushort* __restrict__ Bw,
             float* __restrict__ P, int M, int N, int K, int kslice)
{
    __shared__ ushort As[64][40];
    __shared__ ushort Bs[64][40];
    int tid = threadIdx.x;
    int lane = tid & 63, w = tid >> 6, quad = lane >> 4, l15 = lane & 15;
    int gm = blockIdx.y << 6, gn = blockIdx.x << 6;
    int wr = (w >> 1) << 5, wc = (w & 1) << 5;
    int srow = tid >> 2, sc8 = (tid & 3) << 3;
    int ks = blockIdx.z * kslice;
    f32x4 acc[2][2];
    #pragma unroll
    for (int mi = 0; mi < 2; mi++)
        #pragma unroll
        for (int ni = 0; ni < 2; ni++)
            acc[mi][ni] = (f32x4){0.f,0.f,0.f,0.f};
    const float* Ap = A + (size_t)(gm + srow) * K;
    const ushort* Bp = Bw + (size_t)(gn + srow) * K;
    for (int k0 = ks; k0 < ks + kslice; k0 += 32){
        float4 a0 = *(const float4*)(Ap + k0 + sc8);
        float4 a1 = *(const float4*)(Ap + k0 + sc8 + 4);
        uint4 av;
        av.x = (uint32_t)f2b(a0.x) | ((uint32_t)f2b(a0.y) << 16);
        av.y = (uint32_t)f2b(a0.z) | ((uint32_t)f2b(a0.w) << 16);
        av.z = (uint32_t)f2b(a1.x) | ((uint32_t)f2b(a1.y) << 16);
        av.w = (uint32_t)f2b(a1.z) | ((uint32_t)f2b(a1.w) << 16);
        *(uint4*)&As[srow][sc8] = av;
        *(uint4*)&Bs[srow][sc8] = *(const uint4*)(Bp + k0 + sc8);
        __syncthreads();
        short8 af0 = *(const short8*)&As[wr + l15][quad << 3];
        short8 af1 = *(const short8*)&As[wr + 16 + l15][quad << 3];
        short8 bf0 = *(const short8*)&Bs[wc + l15][quad << 3];
        short8 bf1 = *(const short8*)&Bs[wc + 16 + l15][quad << 3];
        acc[0][0] = __builtin_amdgcn_mfma_f32_16x16x32_bf16(af0, bf0, acc[0][0], 0, 0, 0);
        acc[0][1] = __builtin_amdgcn_mfma_f32_16x16x32_bf16(af0, bf1, acc[0][1], 0, 0, 0);
        acc[1][0] = __builtin_amdgcn_mfma_f32_16x16x32_bf16(af1, bf0, acc[1][0], 0, 0, 0);
        acc[1][1] = __builtin_amdgcn_mfma_f32_16x16x32_bf16(af1, bf1, acc[1][1], 0, 0, 0);
        __syncthreads();
    }
    float* Pz = P + (size_t)blockIdx.z * M * N;
    #pragma unroll
    for (int mi = 0; mi < 2; mi++){
        #pragma unroll
        for (int r = 0; r < 4; r++){
            int row = gm + wr + (mi << 4) + (quad << 2) + r;
            #pragma unroll
            for (int ni = 0; ni < 2; ni++){
                int col = gn + wc + (ni << 4) + l15;
                Pz[(size_t)row * N + col] = acc[mi][ni][r];
            }
        }
    }
}

// ---------------- split-K reduce + bias + scaled ELU (conv epilogue)
__global__ __launch_bounds__(256)
void sk_reduce(const float* __restrict__ P, const float* __restrict__ bias,
               float* __restrict__ C, int MN, int S)
{
    int idx = (blockIdx.x * 256 + threadIdx.x) << 2;
    if (idx >= MN) return;
    float4 s = {0.f, 0.f, 0.f, 0.f};
    for (int z = 0; z < S; z++){
        float4 v = *(const float4*)(P + (size_t)z * MN + idx);
        s.x += v.x; s.y += v.y; s.z += v.z; s.w += v.w;
    }
    const float cscale = 0.9999950000375f;
    int col = idx & 511;
    float o[4] = {s.x, s.y, s.z, s.w};
    #pragma unroll
    for (int t = 0; t < 4; t++){
        float v = (o[t] + bias[col + t]) * cscale;
        o[t] = (v > 0.f) ? v : expm1f(v);
    }
    *(float4*)(C + idx) = (float4){o[0], o[1], o[2], o[3]};
}

// ---------------- semantic sim via split-bf16 MFMA (hi/lo precomputed)
__global__ __launch_bounds__(256)
void sim_mfma(const ushort* __restrict__ XH, const ushort* __restrict__ XL,
              float* __restrict__ SIM){
    __shared__ ushort Ah[64][40], Al[64][40], Bh[64][40], Bl[64][40];
    int x = blockIdx.x, b = blockIdx.y;
    int ti, tj, st, n, goff;
    if (x < 256){ ti = x >> 4; tj = x & 15; st = 0; n = 1024; goff = SG0; }
    else if (x < 272){ int y = x - 256; ti = y >> 2; tj = y & 3; st = 1024; n = 256; goff = SG1; }
    else if (x == 272){ ti = 0; tj = 0; st = 1280; n = 64; goff = SG2; }
    else { ti = 0; tj = 0; st = 1344; n = 16; goff = SG3; }
    const ushort* XbH = XH + (((size_t)b * LT + st) << 9);
    const ushort* XbL = XL + (((size_t)b * LT + st) << 9);
    float* Cb = SIM + (size_t)b * SBT + goff;
    int gm = ti << 6, gn = tj << 6;
    int tid = threadIdx.x;
    int lane = tid & 63, w = tid >> 6, quad = lane >> 4, l15 = lane & 15;
    int wr = (w >> 1) << 5, wc = (w & 1) << 5;
    int srow = tid >> 2, sc8 = (tid & 3) << 3;
    int ra = gm + srow; if (ra > n - 1) ra = n - 1;
    int rb = gn + srow; if (rb > n - 1) rb = n - 1;
    f32x4 acc[2][2];
    #pragma unroll
    for (int mi = 0; mi < 2; mi++)
        #pragma unroll
        for (int ni = 0; ni < 2; ni++)
            acc[mi][ni] = (f32x4){0.f,0.f,0.f,0.f};
    for (int k0 = 0; k0 < 512; k0 += 32){
        *(uint4*)&Ah[srow][sc8] = *(const uint4*)(XbH + ((size_t)ra << 9) + k0 + sc8);
        *(uint4*)&Al[srow][sc8] = *(const uint4*)(XbL + ((size_t)ra << 9) + k0 + sc8);
        *(uint4*)&Bh[srow][sc8] = *(const uint4*)(XbH + ((size_t)rb << 9) + k0 + sc8);
        *(uint4*)&Bl[srow][sc8] = *(const uint4*)(XbL + ((size_t)rb << 9) + k0 + sc8);
        __syncthreads();
        short8 ah0 = *(const short8*)&Ah[wr + l15][quad << 3];
        short8 ah1 = *(const short8*)&Ah[wr + 16 + l15][quad << 3];
        short8 al0 = *(const short8*)&Al[wr + l15][quad << 3];
        short8 al1 = *(const short8*)&Al[wr + 16 + l15][quad << 3];
        short8 bh0 = *(const short8*)&Bh[wc + l15][quad << 3];
        short8 bh1 = *(const short8*)&Bh[wc + 16 + l15][quad << 3];
        short8 bl0 = *(const short8*)&Bl[wc + l15][quad << 3];
        short8 bl1 = *(const short8*)&Bl[wc + 16 + l15][quad << 3];
        acc[0][0] = __builtin_amdgcn_mfma_f32_16x16x32_bf16(ah0, bh0, acc[0][0], 0, 0, 0);
        acc[0][0] = __builtin_amdgcn_mfma_f32_16x16x32_bf16(ah0, bl0, acc[0][0], 0, 0, 0);
        acc[0][0] = __builtin_amdgcn_mfma_f32_16x16x32_bf16(al0, bh0, acc[0][0], 0, 0, 0);
        acc[0][1] = __builtin_amdgcn_mfma_f32_16x16x32_bf16(ah0, bh1, acc[0][1], 0, 0, 0);
        acc[0][1] = __builtin_amdgcn_mfma_f32_16x16x32_bf16(ah0, bl1, acc[0][1], 0, 0, 0);
        acc[0][1] = __builtin_amdgcn_mfma_f32_16x16x32_bf16(al0, bh1, acc[0][1], 0, 0, 0);
        acc[1][0] = __builtin_amdgcn_mfma_f32_16x16x32_bf16(ah1, bh0, acc[1][0], 0, 0, 0);
        acc[1][0] = __builtin_amdgcn_mfma_f32_16x16x32_bf16(ah1, bl0, acc[1][0], 0, 0, 0);
        acc[1][0] = __builtin_amdgcn_mfma_f32_16x16x32_bf16(al1, bh0, acc[1][0], 0, 0, 0);
        acc[1][1] = __builtin_amdgcn_mfma_f32_16x16x32_bf16(ah1, bh1, acc[1][1], 0, 0, 0);
        acc[1][1] = __builtin_amdgcn_mfma_f32_16x16x32_bf16(ah1, bl1, acc[1][1], 0, 0, 0);
        acc[1][1] = __builtin_amdgcn_mfma_f32_16x16x32_bf16(al1, bh1, acc[1][1], 0, 0, 0);
        __syncthreads();
    }
    #pragma unroll
    for (int mi = 0; mi < 2; mi++){
        #pragma unroll
        for (int r = 0; r < 4; r++){
            int row = gm + wr + (mi << 4) + (quad << 2) + r;
            if (row < n){
                #pragma unroll
                for (int ni = 0; ni < 2; ni++){
                    int col = gn + wc + (ni << 4) + l15;
                    if (col < n) Cb[(size_t)row * n + col] = acc[mi][ni][r];
                }
            }
        }
    }
}

// ---------------- concat conv pyramids
__global__ __launch_bounds__(256)
void pcat_copy(const float* __restrict__ C1, const float* __restrict__ C2,
               const float* __restrict__ C3, float* __restrict__ PC){
    int idx = blockIdx.x * 256 + threadIdx.x;
    int d = idx & 511;
    int r = (idx >> 9) % 336;
    int b = idx / (336 * 512);
    float v;
    if (r < 256)       v = C1[(((size_t)b * 256 + r) << 9) + d];
    else if (r < 320)  v = C2[(((size_t)b * 64 + (r - 256)) << 9) + d];
    else               v = C3[(((size_t)b * 16 + (r - 320)) << 9) + d];
    PC[idx] = v;
}

__global__ __launch_bounds__(256)
void xenc_copy(const float* __restrict__ xe, float* __restrict__ dst){
    int idx = blockIdx.x * 256 + threadIdx.x;
    int d = idx & 511;
    int l = (idx >> 9) & 1023;
    int b = idx >> 19;
    dst[(((size_t)b * LT + l) << 9) + d] = xe[idx];
}

// ---------------- LayerNorm over 512, wave per row
__global__ __launch_bounds__(256)
void ln_kernel(const float* __restrict__ in, const float* __restrict__ g,
               const float* __restrict__ bta, float* __restrict__ out, float eps){
    int wid = threadIdx.x >> 6, lane = threadIdx.x & 63;
    int row = blockIdx.x * 4 + wid;
    const float* p = in + ((size_t)row << 9);
    float vals[8]; float s = 0.f, s2 = 0.f;
    #pragma unroll
    for (int t = 0; t < 8; t++){
        float v = p[lane + t * 64]; vals[t] = v; s += v; s2 += v * v;
    }
    #pragma unroll
    for (int off = 32; off; off >>= 1){
        s  += __shfl_xor(s,  off, 64);
        s2 += __shfl_xor(s2, off, 64);
    }
    float mu = s * (1.f / 512.f);
    float var = s2 * (1.f / 512.f) - mu * mu;
    float r = rsqrtf(var + eps);
    float* q = out + ((size_t)row << 9);
    #pragma unroll
    for (int t = 0; t < 8; t++){
        int c = lane + t * 64;
        q[c] = (vals[t] - mu) * r * g[c] + bta[c];
    }
}

// ---------------- LayerNorm + fused add3: X = (T + ln(in) + X)/3
__global__ __launch_bounds__(256)
void ln_add3(const float* __restrict__ in, const float* __restrict__ g,
             const float* __restrict__ bta, const float* __restrict__ T,
             float* __restrict__ X, float eps){
    int wid = threadIdx.x >> 6, lane = threadIdx.x & 63;
    int row = blockIdx.x * 4 + wid;
    const float* p = in + ((size_t)row << 9);
    float vals[8]; float s = 0.f, s2 = 0.f;
    #pragma unroll
    for (int t = 0; t < 8; t++){
        float v = p[lane + t * 64]; vals[t] = v; s += v; s2 += v * v;
    }
    #pragma unroll
    for (int off = 32; off; off >>= 1){
        s  += __shfl_xor(s,  off, 64);
        s2 += __shfl_xor(s2, off, 64);
    }
    float mu = s * (1.f / 512.f);
    float var = s2 * (1.f / 512.f) - mu * mu;
    float r = rsqrtf(var + eps);
    const float* tp = T + ((size_t)row << 9);
    float* xp = X + ((size_t)row << 9);
    #pragma unroll
    for (int t = 0; t < 8; t++){
        int c = lane + t * 64;
        float sn = (vals[t] - mu) * r * g[c] + bta[c];
        xp[c] = (tp[c] + sn + xp[c]) * (1.f / 3.f);
    }
}

// ---------------- row L2-normalize → bf16 hi/lo split
__global__ __launch_bounds__(256)
void rownorm_kernel(const float* __restrict__ in, ushort* __restrict__ XHp,
                    ushort* __restrict__ XLp){
    int wid = threadIdx.x >> 6, lane = threadIdx.x & 63;
    int row = blockIdx.x * 4 + wid;
    const float* p = in + ((size_t)row << 9);
    float vals[8]; float s2 = 0.f;
    #pragma unroll
    for (int t = 0; t < 8; t++){
        float v = p[lane + t * 64]; vals[t] = v; s2 += v * v;
    }
    #pragma unroll
    for (int off = 32; off; off >>= 1) s2 += __shfl_xor(s2, off, 64);
    float inv = 1.f / fmaxf(sqrtf(s2), 1e-8f);
    ushort* qh = XHp + ((size_t)row << 9);
    ushort* ql = XLp + ((size_t)row << 9);
    #pragma unroll
    for (int t = 0; t < 8; t++){
        float v = vals[t] * inv;
        ushort h = f2b(v);
        qh[lane + t * 64] = h;
        ql[lane + t * 64] = f2b(v - b2f(h));
    }
}

// ---------------- top-k: wave-per-row register selection, bitmask output
__global__ __launch_bounds__(256)
void topk_sel(const float* __restrict__ SIM, u64* __restrict__ MB){
    int wid = threadIdx.x >> 6, lane = threadIdx.x & 63;
    int r = blockIdx.x * 4 + wid;        // 0..B*LT-1
    int b = r / LT, i = r % LT;
    int bi, st, n; blk_info(i, bi, st, n);
    u64* mrow = MB + ((size_t)b * LT + i) * MBW;
    u64 myw = 0;
    if (lane == 21) myw = 0xFFFFFFFFFFFF0000ULL;     // pad: keys 1360..1407 banned
    if (n == 16){                                     // all 16 in-block keys banned
        if (lane == 21) myw = ~0ULL;
        if (lane < MBW) mrow[lane] = myw;
        return;
    }
    int goff = (bi == 0) ? SG0 : (bi == 1) ? SG1 : SG2;
    const float* srow = SIM + (size_t)b * SBT + goff + (size_t)(i - st) * n;
    int ns = n >> 6;
    float vals[16];
    #pragma unroll
    for (int t = 0; t < 16; t++)
        vals[t] = (t < ns) ? srow[lane + (t << 6)] : -FLT_MAX;
    for (int it = 0; it < 32; it++){
        float bv = vals[0]; int bt = 0;
        #pragma unroll
        for (int t = 1; t < 16; t++)
            if (vals[t] > bv){ bv = vals[t]; bt = t; }
        int bidx = (bt << 6) + lane;
        #pragma unroll
        for (int off = 1; off < 64; off <<= 1){
            float ov = __shfl_xor(bv, off, 64);
            int   oi = __shfl_xor(bidx, off, 64);
            if (ov > bv || (ov == bv && oi < bidx)){ bv = ov; bidx = oi; }
        }
        int gb = st + bidx;
        if (lane == (gb >> 6)) myw |= 1ULL << (gb & 63);
        if ((bidx & 63) == lane){
            int bt2 = bidx >> 6;
            #pragma unroll
            for (int t = 0; t < 16; t++) if (t == bt2) vals[t] = -FLT_MAX;
        }
    }
    if (lane < MBW) mrow[lane] = myw;
}

// ---------------- sparse temporal attention: prefetched, no-max exp2, coalesced V
__global__ __launch_bounds__(256)
void attn_sparse(const ushort* __restrict__ Q, const ushort* __restrict__ Kp,
                 const ushort* __restrict__ Vn, const int* __restrict__ IDX,
                 const int* __restrict__ CNT, float* __restrict__ O){
    int wid = threadIdx.x >> 6, lane = threadIdx.x & 63;
    int row = blockIdx.x * 4 + wid;
    int b = row / (NHH * LT);
    int rem = row % (NHH * LT);
    int h = rem / LT, i = rem % LT;
    int c = CNT[i];
    int jl = IDX[i * 12 + (lane % 12)];
    float qd = b2f(Q[(((size_t)b * LT + i) << 9) + h * 64 + lane]);
    const ushort* kb = Kp + (((size_t)b * LT) << 9) + h * 64 + lane;
    const ushort* vb = Vn + (((size_t)b * LT) << 9) + h * 64 + lane;
    // broadcast indices, then issue all K/V loads independently (list padded to 12)
    int jj[12];
    #pragma unroll
    for (int t = 0; t < 12; t++) jj[t] = __shfl(jl, t, 64);
    float kv[12], vv[12];
    #pragma unroll
    for (int t = 0; t < 12; t++){
        kv[t] = b2f(kb[(size_t)jj[t] << 9]);
        vv[t] = b2f(vb[(size_t)jj[t] << 9]);
    }
    float lsum = 0.f, o = 0.f;
    #pragma unroll
    for (int t = 0; t < 12; t++){
        float s = qd * kv[t];
        #pragma unroll
        for (int off = 32; off; off >>= 1) s += __shfl_xor(s, off, 64);
        float p = (t < c) ? exp2f(s) : 0.f;   // scores bounded: no max subtraction
        lsum += p;
        o += p * vv[t];
    }
    O[(((size_t)b * LT + i) << 9) + h * 64 + lane] = o / lsum;
}

// ---------------- MFMA flash attention (semantic, bitmask, no online max)
__global__ __launch_bounds__(256)
void flash_mfma(const ushort* __restrict__ Q, const ushort* __restrict__ Kp,
                const ushort* __restrict__ Vt, const u64* __restrict__ MB,
                float* __restrict__ O)
{
    __shared__ ushort Ks[64][72];
    __shared__ ushort Vs[64][72];
    __shared__ u64 Ms64[64];
    __shared__ ushort Ps[4][16][72];
    int bh = blockIdx.y, b = bh >> 3, h = bh & 7;
    int q0 = blockIdx.x << 6;
    int tid = threadIdx.x;
    int w = tid >> 6, lane = tid & 63, quad = lane >> 4, l15 = lane & 15;

    int qm = q0 + w * 16 + l15;
    int qmc = (qm < LT) ? qm : (LT - 1);
    const ushort* qp = Q + ((size_t)(b * LT + qmc) << 9) + h * 64 + (quad << 3);
    short8 qf0 = *(const short8*)qp;
    short8 qf1 = *(const short8*)(qp + 32);

    float l_acc[4] = {0.f, 0.f, 0.f, 0.f};
    f32x4 Oacc[4];
    #pragma unroll
    for (int dt = 0; dt < 4; dt++) Oacc[dt] = (f32x4){0.f,0.f,0.f,0.f};

    int srow = tid >> 2, sc = (tid & 3) << 4;
    const u64* Mbase = MB + (size_t)b * LT * MBW;

    for (int kt = 0; kt < 22; kt++){
        int k0 = kt << 6;
        __syncthreads();
        {
            int krow = k0 + srow; if (krow >= LT) krow = LT - 1;
            const ushort* kp = Kp + ((size_t)(b * LT + krow) << 9) + h * 64 + sc;
            *(uint4*)&Ks[srow][sc]     = *(const uint4*)kp;
            *(uint4*)&Ks[srow][sc + 8] = *(const uint4*)(kp + 8);
            int kbase = k0 + sc; if (kbase > LT - 16) kbase = LT - 16;
            const ushort* vp = Vt + ((size_t)(b * 512 + h * 64 + srow)) * LT + kbase;
            *(uint4*)&Vs[srow][sc]     = *(const uint4*)vp;
            *(uint4*)&Vs[srow][sc + 8] = *(const uint4*)(vp + 8);
            if (tid < 64){
                int mrow = q0 + tid; if (mrow >= LT) mrow = LT - 1;
                Ms64[tid] = Mbase[(size_t)mrow * MBW + kt];
            }
        }
        __syncthreads();
        f32x4 s[4];
        #pragma unroll
        for (int nt = 0; nt < 4; nt++) s[nt] = (f32x4){0.f,0.f,0.f,0.f};
        #pragma unroll
        for (int nt = 0; nt < 4; nt++){
            short8 kf0 = *(const short8*)&Ks[(nt << 4) + l15][quad << 3];
            short8 kf1 = *(const short8*)&Ks[(nt << 4) + l15][32 + (quad << 3)];
            s[nt] = __builtin_amdgcn_mfma_f32_16x16x32_bf16(qf0, kf0, s[nt], 0, 0, 0);
            s[nt] = __builtin_amdgcn_mfma_f32_16x16x32_bf16(qf1, kf1, s[nt], 0, 0, 0);
        }
        #pragma unroll
        for (int r = 0; r < 4; r++){
            int lrow = (w << 4) + (quad << 2) + r;
            u64 bits = Ms64[lrow];
            float psum = 0.f;
            #pragma unroll
            for (int nt = 0; nt < 4; nt++){
                uint32_t bad = (uint32_t)(bits >> (nt * 16 + l15)) & 1u;
                float pv = bad ? 0.f : exp2f(s[nt][r]);
                psum += pv;
                Ps[w][(quad << 2) + r][(nt << 4) + l15] = f2b(pv);
            }
            l_acc[r] += psum;
        }
        short8 pf0 = *(const short8*)&Ps[w][l15][quad << 3];
        short8 pf1 = *(const short8*)&Ps[w][l15][32 + (quad << 3)];
        #pragma unroll
        for (int dt = 0; dt < 4; dt++){
            short8 vf0 = *(const short8*)&Vs[(dt << 4) + l15][quad << 3];
            short8 vf1 = *(const short8*)&Vs[(dt << 4) + l15][32 + (quad << 3)];
            Oacc[dt] = __builtin_amdgcn_mfma_f32_16x16x32_bf16(pf0, vf0, Oacc[dt], 0, 0, 0);
            Oacc[dt] = __builtin_amdgcn_mfma_f32_16x16x32_bf16(pf1, vf1, Oacc[dt], 0, 0, 0);
        }
    }
    #pragma unroll
    for (int r = 0; r < 4; r++){
        #pragma unroll
        for (int off = 1; off < 16; off <<= 1)
            l_acc[r] += __shfl_xor(l_acc[r], off, 64);
    }
    #pragma unroll
    for (int r = 0; r < 4; r++){
        int qrow = q0 + (w << 4) + (quad << 2) + r;
        if (qrow < LT){
            float inv = 1.f / l_acc[r];
            #pragma unroll
            for (int dt = 0; dt < 4; dt++)
                O[((size_t)(b * LT + qrow) << 9) + h * 64 + (dt << 4) + l15] = Oacc[dt][r] * inv;
        }
    }
}

extern "C" void kernel_launch(void* const* d_in, const int* in_sizes, int n_in,
                              void* d_out, int out_size, void* d_ws, size_t ws_size,
                              hipStream_t stream)
{
    const float* x_enc   = (const float*)d_in[0];
    const float* down_W  = (const float*)d_in[1];
    const float* down_b  = (const float*)d_in[2];
    const float* conv_W  = (const float*)d_in[3];
    const float* conv_b  = (const float*)d_in[4];
    const float* up_W    = (const float*)d_in[5];
    const float* up_b    = (const float*)d_in[6];
    const float* bc_g    = (const float*)d_in[7];
    const float* bc_b    = (const float*)d_in[8];
    const float* aWq     = (const float*)d_in[9];
    const float* aWk     = (const float*)d_in[10];
    const float* aWv     = (const float*)d_in[11];
    const float* afcW    = (const float*)d_in[12];
    const float* afcb    = (const float*)d_in[13];
    const float* alng    = (const float*)d_in[14];
    const float* alnb    = (const float*)d_in[15];
    const float* fW1     = (const float*)d_in[16];
    const float* fb1     = (const float*)d_in[17];
    const float* fW2     = (const float*)d_in[18];
    const float* fb2     = (const float*)d_in[19];
    const float* flng    = (const float*)d_in[20];
    const float* flnb    = (const float*)d_in[21];

    const size_t NBL = (size_t)NBLE;
    float* X   = (float*)d_ws;
    float* TMP = X   + NBL;
    float* Qb  = TMP + NBL;
    float* Kb  = Qb  + NBL;
    float* Vb  = Kb  + NBL;
    float* AO  = Vb  + NBL;
    float* TO  = AO  + NBL;
    float* SO  = TO  + NBL;
    u64* MBm = (u64*)(SO + NBL);                      // B*LT*24 words
    int* TIDX = (int*)(MBm + (size_t)BB * LT * MBW);
    int* TCNT = TIDX + (size_t)LT * 12;
    ushort* WG = (ushort*)(TCNT + LT);
    const size_t M512 = 262144;
    ushort* WdownT = WG;                 size_t wo = M512;
    ushort* WupT   = WG + wo;            wo += M512;
    ushort* Wqkv   = WG + wo;            wo += 12 * M512;   // 4 layers x [Wq|Wk|Wv]^T
    ushort* WfT    = WG + wo;            wo += 4 * M512;
    ushort* W1T    = WG + wo;            wo += 2 * M512;
    ushort* W2T    = WG + wo;            wo += 2 * M512;
    ushort* WCt    = WG + wo;            wo += 3 * 1048576;
    size_t need = 8 * NBL * sizeof(float) + (size_t)BB * LT * MBW * 8
                + (size_t)LT * 13 * 4 + wo * sizeof(ushort);
    if (ws_size < need) return;

    // aliases (lifetimes disjoint)
    float* Y    = Qb;
    float* C1   = Kb;
    float* C2   = C1 + (size_t)BB*256*512;
    float* C3   = C2 + (size_t)BB*64*512;
    float* PCAT = Vb;
    float* SKP  = AO;                     // split-K partials (bottleneck only)
    ushort* XNh = (ushort*)AO;            // hi/lo bf16 normalized rows
    ushort* XNl = XNh + NBL;
    float* SIMB = Qb;
    float* Hf   = Qb;
    ushort* QbH = (ushort*)Qb;
    ushort* KbH = (ushort*)Kb;
    ushort* VtH = (ushort*)Vb;            // V^T in first half of Vb
    ushort* VnH = VtH + NBL;              // V normal layout in second half of Vb

    auto gemmB = [&](const float* A, const ushort* Bw, const float* bias,
                     const float* res, void* C, int M, int N, int K,
                     int act, int omode, int mpb, int orpb, int ooff){
        dim3 grid(N / 128, M / 64);
        gemm_bf16<<<grid, 256, 0, stream>>>(A, Bw, bias, res, C, M, N, K,
                                            act, omode, mpb, orpb, ooff);
    };
    auto convG = [&](const float* A, const ushort* Bw, const float* bias,
                     float* C, int M){
        const int S = 8, K = 2048, N = 512;
        gemm_sk<<<dim3(8, M / 64, S), 256, 0, stream>>>(A, Bw, SKP, M, N, K, K / S);
        sk_reduce<<<(M * N) / 1024, 256, 0, stream>>>(SKP, bias, C, M * N, S);
    };

    build_tidx<<<(LT + 255) / 256, 256, 0, stream>>>(TIDX, TCNT);
    wtrans<<<dim3(8, 8, 1), 256, 0, stream>>>(down_W, WdownT, 512, 512, M512);
    wtrans<<<dim3(8, 8, 1), 256, 0, stream>>>(up_W,   WupT,   512, 512, M512);
    wtrans<<<dim3(8, 8, 4), 256, 0, stream>>>(aWq,  Wqkv + 0 * M512, 512, 512, 3 * (long)M512);
    wtrans<<<dim3(8, 8, 4), 256, 0, stream>>>(aWk,  Wqkv + 1 * M512, 512, 512, 3 * (long)M512);
    wtrans<<<dim3(8, 8, 4), 256, 0, stream>>>(aWv,  Wqkv + 2 * M512, 512, 512, 3 * (long)M512);
    wtrans<<<dim3(8, 8, 4), 256, 0, stream>>>(afcW, WfT, 512, 512, M512);
    wtrans<<<dim3(8, 8, 2), 256, 0, stream>>>(fW1,  W1T, 512, 512, M512);
    wtrans<<<dim3(8, 8, 2), 256, 0, stream>>>(fW2,  W2T, 512, 512, M512);
    wconv<<<dim3(4096, 3), 256, 0, stream>>>(conv_W, WCt);

    // ---- bottleneck (conv chain via split-K: tiny M needs K-parallelism)
    gemmB(x_enc, WdownT, down_b, nullptr, Y, BB*1024, 512, 512, 0, 0, 0, 0, 0);
    convG(Y,  WCt,             conv_b + 0,    C1, BB*256);
    convG(C1, WCt + 1048576,   conv_b + 512,  C2, BB*64);
    convG(C2, WCt + 2*1048576, conv_b + 1024, C3, BB*16);
    pcat_copy<<<(BB*336*512)/256, 256, 0, stream>>>(C1, C2, C3, PCAT);
    gemmB(PCAT, WupT, up_b, nullptr, TMP, BB*336, 512, 512, 0, 0, 336, LT, 1024);
    xenc_copy<<<(BB*1024*512)/256, 256, 0, stream>>>(x_enc, TMP);
    ln_kernel<<<(BB*LT)/4, 256, 0, stream>>>(TMP, bc_g, bc_b, X, 1e-5f);

    // ---- transformer layers
    for (int l = 0; l < 2; l++){
        rownorm_kernel<<<(BB*LT)/4, 256, 0, stream>>>(X, XNh, XNl);
        sim_mfma<<<dim3(274, BB), 256, 0, stream>>>(XNh, XNl, SIMB);
        topk_sel<<<(BB*LT)/4, 256, 0, stream>>>(SIMB, MBm);

        for (int j = 0; j < 2; j++){
            int li = l * 2 + j;
            const float* bf = afcb + (size_t)li * 512;
            const float* lg = alng + (size_t)li * 512;
            const float* lb = alnb + (size_t)li * 512;
            // fused QKV projection: Q(scaled)->QbH, K->KbH, V^T->VtH, V->VnH
            gemmB(X, Wqkv + (size_t)li * 3 * M512, nullptr, nullptr, QbH,
                  BB*LT, 1536, 512, 0, 3, 0, 0, 0);
            if (j == 0)
                attn_sparse<<<(BB*NHH*LT)/4, 256, 0, stream>>>(QbH, KbH, VnH, TIDX, TCNT, AO);
            else
                flash_mfma<<<dim3(22, 32), 256, 0, stream>>>(QbH, KbH, VtH, MBm, AO);
            gemmB(AO, WfT + (size_t)li * M512, bf, X, TMP, BB*LT, 512, 512, 0, 0, 0, 0, 0);
            if (j == 0)
                ln_kernel<<<(BB*LT)/4, 256, 0, stream>>>(TMP, lg, lb, TO, 1e-6f);
            else
                ln_add3<<<(BB*LT)/4, 256, 0, stream>>>(TMP, lg, lb, TO, X, 1e-6f);
        }

        // FFN
        gemmB(X,  W1T + (size_t)l * M512, fb1 + (size_t)l*512, nullptr, Hf, BB*LT, 512, 512, 2, 0, 0, 0, 0);
        gemmB(Hf, W2T + (size_t)l * M512, fb2 + (size_t)l*512, X, TMP, BB*LT, 512, 512, 0, 0, 0, 0, 0);
        ln_kernel<<<(BB*LT)/4, 256, 0, stream>>>(TMP, flng + (size_t)l*512, flnb + (size_t)l*512,
                                                 (l == 1) ? (float*)d_out : X, 1e-6f);
    }
}

// Round 11
// 941.261 us; speedup vs baseline: 1.3117x; 1.0963x over previous
//
#include <hip/hip_runtime.h>
#include <float.h>
#include <math.h>
#include <stdint.h>

#define LT 1360
#define BB 4
#define DM 512
#define NHH 8
#define NBLE 2785280   // BB*LT*512 elements
#define MBW 24         // mask words (uint64) per row
#define QSCALE 0.18033688f   // 0.125 * log2(e)

typedef __attribute__((ext_vector_type(8))) short short8;
typedef __attribute__((ext_vector_type(4))) float f32x4;
typedef unsigned long long u64;

__device__ __forceinline__ ushort f2b(float x){
    uint32_t u = __float_as_uint(x);
    return (ushort)((u + 0x7fffu + ((u >> 16) & 1u)) >> 16);
}
__device__ __forceinline__ float b2f(ushort u){
    return __uint_as_float(((uint32_t)u) << 16);
}

// semantic sim buffer layout (per batch)
#define SG0 0
#define SG1 1048576
#define SG2 (SG1 + 65536)
#define SG3 (SG2 + 4096)
#define SBT (SG3 + 256)

__device__ __forceinline__ void blk_info(int i, int& bi, int& st, int& n){
    if (i < 1024){ bi = 0; st = 0;    n = 1024; }
    else if (i < 1280){ bi = 1; st = 1024; n = 256; }
    else if (i < 1344){ bi = 2; st = 1280; n = 64; }
    else { bi = 3; st = 1344; n = 16; }
}

// ---------------- temporal allowed-index lists (padded to 12 for speculative loads)
__global__ __launch_bounds__(256)
void build_tidx(int* __restrict__ idx, int* __restrict__ cnt){
    int i = blockIdx.x * 256 + threadIdx.x;
    if (i >= LT) return;
    int bi, st, n; blk_info(i, bi, st, n);
    int c = 0; int* row = idx + i * 12;
    int lo = (i - 2 > st) ? i - 2 : st;
    int hi = (i + 2 < st + n - 1) ? i + 2 : st + n - 1;
    for (int j = lo; j <= hi; j++) row[c++] = j;
    if (bi < 3) row[c++] = st + n + (i - st) / 4;
    if (bi > 0){
        int stc = st - n * 4;
        int base = stc + (i - st) * 4;
        for (int t = 0; t < 4; t++) row[c++] = base + t;
    }
    cnt[i] = c;
    for (int t = c; t < 12; t++) row[t] = 0;   // safe pad
}

// ---------------- weight transpose+cast: Wd[n*K+k] = bf16(Ws[k*N+n])
__global__ __launch_bounds__(256)
void wtrans(const float* __restrict__ W, ushort* __restrict__ Wt, int K, int N, long dstStride){
    int mat = blockIdx.z;
    const float* Ws = W + (size_t)mat * K * N;
    ushort* Wd = Wt + (size_t)mat * dstStride;
    int k0 = blockIdx.y << 6, n0 = blockIdx.x << 6;
    __shared__ ushort t[64][72];
    int tid = threadIdx.x;
    #pragma unroll
    for (int p = 0; p < 4; p++){
        int idx = tid + (p << 8);
        int r = idx >> 4, c4 = (idx & 15) << 2;
        float4 v = *(const float4*)(Ws + (size_t)(k0 + r) * N + n0 + c4);
        t[c4+0][r] = f2b(v.x); t[c4+1][r] = f2b(v.y);
        t[c4+2][r] = f2b(v.z); t[c4+3][r] = f2b(v.w);
    }
    __syncthreads();
    #pragma unroll
    for (int p = 0; p < 4; p++){
        int idx = tid + (p << 8);
        int r = idx >> 4, c4 = (idx & 15) << 2;
        *(uint2*)&Wd[(size_t)(n0 + r) * K + k0 + c4] = *(uint2*)&t[r][c4];
    }
}

// ---------------- conv weight repack+cast
__global__ __launch_bounds__(256)
void wconv(const float* __restrict__ cw, ushort* __restrict__ wt){
    int conv = blockIdx.y;
    const float* src = cw + (size_t)conv * 512 * 512 * 4;
    ushort* dst = wt + (size_t)conv * 2048 * 512;
    int idx = blockIdx.x * 256 + threadIdx.x;
    int o = idx >> 11, rest = idx & 2047;
    int k = rest >> 9, ii = rest & 511;
    dst[idx] = f2b(src[((size_t)(o << 9) + ii) * 4 + k]);
}

// ---------------- bf16 MFMA GEMM, 64x128 tile, BK=32 (used for QKV, N=1536)
// omode: 0 f32 out (+row remap), 1 bf16 out, 3 fused QKV out (Q scaled, V dual-layout)
__global__ __launch_bounds__(256)
void gemm_bf16(const float* __restrict__ A, const ushort* __restrict__ Bw,
               const float* __restrict__ bias, const float* __restrict__ Rres,
               void* __restrict__ Cout, int M, int N, int K,
               int act, int omode, int mpb, int orpb, int ooff)
{
    __shared__ ushort As[64][40];
    __shared__ ushort Bs[128][40];
    int tid = threadIdx.x;
    int lane = tid & 63, w = tid >> 6, quad = lane >> 4, l15 = lane & 15;
    int gm = blockIdx.y << 6, gn = blockIdx.x << 7;
    int arow = tid >> 2, ac8 = (tid & 3) << 3;
    int brow = tid >> 1, bc16 = (tid & 1) << 4;
    f32x4 acc[4][2];
    #pragma unroll
    for (int mi = 0; mi < 4; mi++)
        #pragma unroll
        for (int ni = 0; ni < 2; ni++)
            acc[mi][ni] = (f32x4){0.f,0.f,0.f,0.f};
    const float* Ap = A + (size_t)(gm + arow) * K;
    const ushort* Bp = Bw + (size_t)(gn + brow) * K;
    for (int k0 = 0; k0 < K; k0 += 32){
        float4 a0 = *(const float4*)(Ap + k0 + ac8);
        float4 a1 = *(const float4*)(Ap + k0 + ac8 + 4);
        uint4 av;
        av.x = (uint32_t)f2b(a0.x) | ((uint32_t)f2b(a0.y) << 16);
        av.y = (uint32_t)f2b(a0.z) | ((uint32_t)f2b(a0.w) << 16);
        av.z = (uint32_t)f2b(a1.x) | ((uint32_t)f2b(a1.y) << 16);
        av.w = (uint32_t)f2b(a1.z) | ((uint32_t)f2b(a1.w) << 16);
        *(uint4*)&As[arow][ac8] = av;
        *(uint4*)&Bs[brow][bc16]     = *(const uint4*)(Bp + k0 + bc16);
        *(uint4*)&Bs[brow][bc16 + 8] = *(const uint4*)(Bp + k0 + bc16 + 8);
        __syncthreads();
        short8 af[4], bf[2];
        #pragma unroll
        for (int mi = 0; mi < 4; mi++) af[mi] = *(const short8*)&As[(mi << 4) + l15][quad << 3];
        #pragma unroll
        for (int ni = 0; ni < 2; ni++) bf[ni] = *(const short8*)&Bs[(w << 5) + (ni << 4) + l15][quad << 3];
        #pragma unroll
        for (int mi = 0; mi < 4; mi++)
            #pragma unroll
            for (int ni = 0; ni < 2; ni++)
                acc[mi][ni] = __builtin_amdgcn_mfma_f32_16x16x32_bf16(af[mi], bf[ni], acc[mi][ni], 0, 0, 0);
        __syncthreads();
    }
    #pragma unroll
    for (int mi = 0; mi < 4; mi++){
        #pragma unroll
        for (int r = 0; r < 4; r++){
            int row = gm + (mi << 4) + (quad << 2) + r;
            #pragma unroll
            for (int ni = 0; ni < 2; ni++){
                int col = gn + (w << 5) + (ni << 4) + l15;
                float v = acc[mi][ni][r];
                if (bias) v += bias[col];
                if (Rres) v += Rres[(size_t)row * N + col];
                if (act == 2){ v = fmaxf(v, 0.f); }
                if (omode == 0){
                    int orow = mpb ? (row / mpb) * orpb + ooff + (row % mpb) : row;
                    ((float*)Cout)[(size_t)orow * N + col] = v;
                } else if (omode == 1){
                    ((ushort*)Cout)[(size_t)row * N + col] = f2b(v);
                } else {
                    int seg = col >> 9, c5 = col & 511;
                    ushort* Ob = (ushort*)Cout;
                    if (seg == 0)      Ob[(size_t)row * 512 + c5] = f2b(v * QSCALE);
                    else if (seg == 1) Ob[(size_t)2*NBLE + (size_t)row * 512 + c5] = f2b(v);
                    else {
                        int bb = row / LT, ii = row - bb * LT;
                        ushort hv = f2b(v);
                        Ob[(size_t)4*NBLE + ((size_t)(bb * 512 + c5)) * LT + ii] = hv;  // V^T (flash)
                        Ob[(size_t)5*NBLE + (size_t)row * 512 + c5] = hv;               // V normal (sparse)
                    }
                }
            }
        }
    }
}

// ---------------- bf16 MFMA GEMM, 64x64 tile (N=512 GEMMs: 2x the blocks of 64x128)
__global__ __launch_bounds__(256)
void gemm64(const float* __restrict__ A, const ushort* __restrict__ Bw,
            const float* __restrict__ bias, const float* __restrict__ Rres,
            void* __restrict__ Cout, int M, int N, int K,
            int act, int omode, int mpb, int orpb, int ooff)
{
    __shared__ ushort As[64][40];
    __shared__ ushort Bs[64][40];
    int tid = threadIdx.x;
    int lane = tid & 63, w = tid >> 6, quad = lane >> 4, l15 = lane & 15;
    int gm = blockIdx.y << 6, gn = blockIdx.x << 6;
    int wr = (w >> 1) << 5, wc = (w & 1) << 5;
    int srow = tid >> 2, sc8 = (tid & 3) << 3;
    f32x4 acc[2][2];
    #pragma unroll
    for (int mi = 0; mi < 2; mi++)
        #pragma unroll
        for (int ni = 0; ni < 2; ni++)
            acc[mi][ni] = (f32x4){0.f,0.f,0.f,0.f};
    const float* Ap = A + (size_t)(gm + srow) * K;
    const ushort* Bp = Bw + (size_t)(gn + srow) * K;
    for (int k0 = 0; k0 < K; k0 += 32){
        float4 a0 = *(const float4*)(Ap + k0 + sc8);
        float4 a1 = *(const float4*)(Ap + k0 + sc8 + 4);
        uint4 av;
        av.x = (uint32_t)f2b(a0.x) | ((uint32_t)f2b(a0.y) << 16);
        av.y = (uint32_t)f2b(a0.z) | ((uint32_t)f2b(a0.w) << 16);
        av.z = (uint32_t)f2b(a1.x) | ((uint32_t)f2b(a1.y) << 16);
        av.w = (uint32_t)f2b(a1.z) | ((uint32_t)f2b(a1.w) << 16);
        *(uint4*)&As[srow][sc8] = av;
        *(uint4*)&Bs[srow][sc8] = *(const uint4*)(Bp + k0 + sc8);
        __syncthreads();
        short8 af0 = *(const short8*)&As[wr + l15][quad << 3];
        short8 af1 = *(const short8*)&As[wr + 16 + l15][quad << 3];
        short8 bf0 = *(const short8*)&Bs[wc + l15][quad << 3];
        short8 bf1 = *(const short8*)&Bs[wc + 16 + l15][quad << 3];
        acc[0][0] = __builtin_amdgcn_mfma_f32_16x16x32_bf16(af0, bf0, acc[0][0], 0, 0, 0);
        acc[0][1] = __builtin_amdgcn_mfma_f32_16x16x32_bf16(af0, bf1, acc[0][1], 0, 0, 0);
        acc[1][0] = __builtin_amdgcn_mfma_f32_16x16x32_bf16(af1, bf0, acc[1][0], 0, 0, 0);
        acc[1][1] = __builtin_amdgcn_mfma_f32_16x16x32_bf16(af1, bf1, acc[1][1], 0, 0, 0);
        __syncthreads();
    }
    #pragma unroll
    for (int mi = 0; mi < 2; mi++){
        #pragma unroll
        for (int r = 0; r < 4; r++){
            int row = gm + wr + (mi << 4) + (quad << 2) + r;
            #pragma unroll
            for (int ni = 0; ni < 2; ni++){
                int col = gn + wc + (ni << 4) + l15;
                float v = acc[mi][ni][r];
                if (bias) v += bias[col];
                if (Rres) v += Rres[(size_t)row * N + col];
                if (act == 2){ v = fmaxf(v, 0.f); }
                if (omode == 0){
                    int orow = mpb ? (row / mpb) * orpb + ooff + (row % mpb) : row;
                    ((float*)Cout)[(size_t)orow * N + col] = v;
                } else {
                    ((ushort*)Cout)[(size_t)row * N + col] = f2b(v);
                }
            }
        }
    }
}

// ---------------- split-K bf16 GEMM for tiny-M conv chain: 64x64 tile, fp32 partials
__global__ __launch_bounds__(256)
void gemm_sk(const float* __restrict__ A, const ushort* __restrict__ Bw,
             float* __restrict__ P, int M, int N, int K, int kslice)
{
    __shared__ ushort As[64][40];
    __shared__ ushort Bs[64][40];
    int tid = threadIdx.x;
    int lane = tid & 63, w = tid >> 6, quad = lane >> 4, l15 = lane & 15;
    int gm = blockIdx.y << 6, gn = blockIdx.x << 6;
    int wr = (w >> 1) << 5, wc = (w & 1) << 5;
    int srow = tid >> 2, sc8 = (tid & 3) << 3;
    int ks = blockIdx.z * kslice;
    f32x4 acc[2][2];
    #pragma unroll
    for (int mi = 0; mi < 2; mi++)
        #pragma unroll
        for (int ni = 0; ni < 2; ni++)
            acc[mi][ni] = (f32x4){0.f,0.f,0.f,0.f};
    const float* Ap = A + (size_t)(gm + srow) * K;
    const ushort* Bp = Bw + (size_t)(gn + srow) * K;
    for (int k0 = ks; k0 < ks + kslice; k0 += 32){
        float4 a0 = *(const float4*)(Ap + k0 + sc8);
        float4 a1 = *(const float4*)(Ap + k0 + sc8 + 4);
        uint4 av;
        av.x = (uint32_t)f2b(a0.x) | ((uint32_t)f2b(a0.y) << 16);
        av.y = (uint32_t)f2b(a0.z) | ((uint32_t)f2b(a0.w) << 16);
        av.z = (uint32_t)f2b(a1.x) | ((uint32_t)f2b(a1.y) << 16);
        av.w = (uint32_t)f2b(a1.z) | ((uint32_t)f2b(a1.w) << 16);
        *(uint4*)&As[srow][sc8] = av;
        *(uint4*)&Bs[srow][sc8] = *(const uint4*)(Bp + k0 + sc8);
        __syncthreads();
        short8 af0 = *(const short8*)&As[wr + l15][quad << 3];
        short8 af1 = *(const short8*)&As[wr + 16 + l15][quad << 3];
        short8 bf0 = *(const short8*)&Bs[wc + l15][quad << 3];
        short8 bf1 = *(const short8*)&Bs[wc + 16 + l15][quad << 3];
        acc[0][0] = __builtin_amdgcn_mfma_f32_16x16x32_bf16(af0, bf0, acc[0][0], 0, 0, 0);
        acc[0][1] = __builtin_amdgcn_mfma_f32_16x16x32_bf16(af0, bf1, acc[0][1], 0, 0, 0);
        acc[1][0] = __builtin_amdgcn_mfma_f32_16x16x32_bf16(af1, bf0, acc[1][0], 0, 0, 0);
        acc[1][1] = __builtin_amdgcn_mfma_f32_16x16x32_bf16(af1, bf1, acc[1][1], 0, 0, 0);
        __syncthreads();
    }
    float* Pz = P + (size_t)blockIdx.z * M * N;
    #pragma unroll
    for (int mi = 0; mi < 2; mi++){
        #pragma unroll
        for (int r = 0; r < 4; r++){
            int row = gm + wr + (mi << 4) + (quad << 2) + r;
            #pragma unroll
            for (int ni = 0; ni < 2; ni++){
                int col = gn + wc + (ni << 4) + l15;
                Pz[(size_t)row * N + col] = acc[mi][ni][r];
            }
        }
    }
}

// ---------------- split-K reduce + bias + scaled ELU (conv epilogue)
__global__ __launch_bounds__(256)
void sk_reduce(const float* __restrict__ P, const float* __restrict__ bias,
               float* __restrict__ C, int MN, int S)
{
    int idx = (blockIdx.x * 256 + threadIdx.x) << 2;
    if (idx >= MN) return;
    float4 s = {0.f, 0.f, 0.f, 0.f};
    for (int z = 0; z < S; z++){
        float4 v = *(const float4*)(P + (size_t)z * MN + idx);
        s.x += v.x; s.y += v.y; s.z += v.z; s.w += v.w;
    }
    const float cscale = 0.9999950000375f;
    int col = idx & 511;
    float o[4] = {s.x, s.y, s.z, s.w};
    #pragma unroll
    for (int t = 0; t < 4; t++){
        float v = (o[t] + bias[col + t]) * cscale;
        o[t] = (v > 0.f) ? v : expm1f(v);
    }
    *(float4*)(C + idx) = (float4){o[0], o[1], o[2], o[3]};
}

// ---------------- semantic sim via split-bf16 MFMA (hi/lo precomputed)
__global__ __launch_bounds__(256)
void sim_mfma(const ushort* __restrict__ XH, const ushort* __restrict__ XL,
              float* __restrict__ SIM){
    __shared__ ushort Ah[64][40], Al[64][40], Bh[64][40], Bl[64][40];
    int x = blockIdx.x, b = blockIdx.y;
    int ti, tj, st, n, goff;
    if (x < 256){ ti = x >> 4; tj = x & 15; st = 0; n = 1024; goff = SG0; }
    else if (x < 272){ int y = x - 256; ti = y >> 2; tj = y & 3; st = 1024; n = 256; goff = SG1; }
    else if (x == 272){ ti = 0; tj = 0; st = 1280; n = 64; goff = SG2; }
    else { ti = 0; tj = 0; st = 1344; n = 16; goff = SG3; }
    const ushort* XbH = XH + (((size_t)b * LT + st) << 9);
    const ushort* XbL = XL + (((size_t)b * LT + st) << 9);
    float* Cb = SIM + (size_t)b * SBT + goff;
    int gm = ti << 6, gn = tj << 6;
    int tid = threadIdx.x;
    int lane = tid & 63, w = tid >> 6, quad = lane >> 4, l15 = lane & 15;
    int wr = (w >> 1) << 5, wc = (w & 1) << 5;
    int srow = tid >> 2, sc8 = (tid & 3) << 3;
    int ra = gm + srow; if (ra > n - 1) ra = n - 1;
    int rb = gn + srow; if (rb > n - 1) rb = n - 1;
    f32x4 acc[2][2];
    #pragma unroll
    for (int mi = 0; mi < 2; mi++)
        #pragma unroll
        for (int ni = 0; ni < 2; ni++)
            acc[mi][ni] = (f32x4){0.f,0.f,0.f,0.f};
    for (int k0 = 0; k0 < 512; k0 += 32){
        *(uint4*)&Ah[srow][sc8] = *(const uint4*)(XbH + ((size_t)ra << 9) + k0 + sc8);
        *(uint4*)&Al[srow][sc8] = *(const uint4*)(XbL + ((size_t)ra << 9) + k0 + sc8);
        *(uint4*)&Bh[srow][sc8] = *(const uint4*)(XbH + ((size_t)rb << 9) + k0 + sc8);
        *(uint4*)&Bl[srow][sc8] = *(const uint4*)(XbL + ((size_t)rb << 9) + k0 + sc8);
        __syncthreads();
        short8 ah0 = *(const short8*)&Ah[wr + l15][quad << 3];
        short8 ah1 = *(const short8*)&Ah[wr + 16 + l15][quad << 3];
        short8 al0 = *(const short8*)&Al[wr + l15][quad << 3];
        short8 al1 = *(const short8*)&Al[wr + 16 + l15][quad << 3];
        short8 bh0 = *(const short8*)&Bh[wc + l15][quad << 3];
        short8 bh1 = *(const short8*)&Bh[wc + 16 + l15][quad << 3];
        short8 bl0 = *(const short8*)&Bl[wc + l15][quad << 3];
        short8 bl1 = *(const short8*)&Bl[wc + 16 + l15][quad << 3];
        acc[0][0] = __builtin_amdgcn_mfma_f32_16x16x32_bf16(ah0, bh0, acc[0][0], 0, 0, 0);
        acc[0][0] = __builtin_amdgcn_mfma_f32_16x16x32_bf16(ah0, bl0, acc[0][0], 0, 0, 0);
        acc[0][0] = __builtin_amdgcn_mfma_f32_16x16x32_bf16(al0, bh0, acc[0][0], 0, 0, 0);
        acc[0][1] = __builtin_amdgcn_mfma_f32_16x16x32_bf16(ah0, bh1, acc[0][1], 0, 0, 0);
        acc[0][1] = __builtin_amdgcn_mfma_f32_16x16x32_bf16(ah0, bl1, acc[0][1], 0, 0, 0);
        acc[0][1] = __builtin_amdgcn_mfma_f32_16x16x32_bf16(al0, bh1, acc[0][1], 0, 0, 0);
        acc[1][0] = __builtin_amdgcn_mfma_f32_16x16x32_bf16(ah1, bh0, acc[1][0], 0, 0, 0);
        acc[1][0] = __builtin_amdgcn_mfma_f32_16x16x32_bf16(ah1, bl0, acc[1][0], 0, 0, 0);
        acc[1][0] = __builtin_amdgcn_mfma_f32_16x16x32_bf16(al1, bh0, acc[1][0], 0, 0, 0);
        acc[1][1] = __builtin_amdgcn_mfma_f32_16x16x32_bf16(ah1, bh1, acc[1][1], 0, 0, 0);
        acc[1][1] = __builtin_amdgcn_mfma_f32_16x16x32_bf16(ah1, bl1, acc[1][1], 0, 0, 0);
        acc[1][1] = __builtin_amdgcn_mfma_f32_16x16x32_bf16(al1, bh1, acc[1][1], 0, 0, 0);
        __syncthreads();
    }
    #pragma unroll
    for (int mi = 0; mi < 2; mi++){
        #pragma unroll
        for (int r = 0; r < 4; r++){
            int row = gm + wr + (mi << 4) + (quad << 2) + r;
            if (row < n){
                #pragma unroll
                for (int ni = 0; ni < 2; ni++){
                    int col = gn + wc + (ni << 4) + l15;
                    if (col < n) Cb[(size_t)row * n + col] = acc[mi][ni][r];
                }
            }
        }
    }
}

// ---------------- concat conv pyramids
__global__ __launch_bounds__(256)
void pcat_copy(const float* __restrict__ C1, const float* __restrict__ C2,
               const float* __restrict__ C3, float* __restrict__ PC){
    int idx = blockIdx.x * 256 + threadIdx.x;
    int d = idx & 511;
    int r = (idx >> 9) % 336;
    int b = idx / (336 * 512);
    float v;
    if (r < 256)       v = C1[(((size_t)b * 256 + r) << 9) + d];
    else if (r < 320)  v = C2[(((size_t)b * 64 + (r - 256)) << 9) + d];
    else               v = C3[(((size_t)b * 16 + (r - 320)) << 9) + d];
    PC[idx] = v;
}

__global__ __launch_bounds__(256)
void xenc_copy(const float* __restrict__ xe, float* __restrict__ dst){
    int idx = blockIdx.x * 256 + threadIdx.x;
    int d = idx & 511;
    int l = (idx >> 9) & 1023;
    int b = idx >> 19;
    dst[(((size_t)b * LT + l) << 9) + d] = xe[idx];
}

// ---------------- LayerNorm over 512, wave per row
__global__ __launch_bounds__(256)
void ln_kernel(const float* __restrict__ in, const float* __restrict__ g,
               const float* __restrict__ bta, float* __restrict__ out, float eps){
    int wid = threadIdx.x >> 6, lane = threadIdx.x & 63;
    int row = blockIdx.x * 4 + wid;
    const float* p = in + ((size_t)row << 9);
    float vals[8]; float s = 0.f, s2 = 0.f;
    #pragma unroll
    for (int t = 0; t < 8; t++){
        float v = p[lane + t * 64]; vals[t] = v; s += v; s2 += v * v;
    }
    #pragma unroll
    for (int off = 32; off; off >>= 1){
        s  += __shfl_xor(s,  off, 64);
        s2 += __shfl_xor(s2, off, 64);
    }
    float mu = s * (1.f / 512.f);
    float var = s2 * (1.f / 512.f) - mu * mu;
    float r = rsqrtf(var + eps);
    float* q = out + ((size_t)row << 9);
    #pragma unroll
    for (int t = 0; t < 8; t++){
        int c = lane + t * 64;
        q[c] = (vals[t] - mu) * r * g[c] + bta[c];
    }
}

// ---------------- LayerNorm + fused add3: X = (T + ln(in) + X)/3
__global__ __launch_bounds__(256)
void ln_add3(const float* __restrict__ in, const float* __restrict__ g,
             const float* __restrict__ bta, const float* __restrict__ T,
             float* __restrict__ X, float eps){
    int wid = threadIdx.x >> 6, lane = threadIdx.x & 63;
    int row = blockIdx.x * 4 + wid;
    const float* p = in + ((size_t)row << 9);
    float vals[8]; float s = 0.f, s2 = 0.f;
    #pragma unroll
    for (int t = 0; t < 8; t++){
        float v = p[lane + t * 64]; vals[t] = v; s += v; s2 += v * v;
    }
    #pragma unroll
    for (int off = 32; off; off >>= 1){
        s  += __shfl_xor(s,  off, 64);
        s2 += __shfl_xor(s2, off, 64);
    }
    float mu = s * (1.f / 512.f);
    float var = s2 * (1.f / 512.f) - mu * mu;
    float r = rsqrtf(var + eps);
    const float* tp = T + ((size_t)row << 9);
    float* xp = X + ((size_t)row << 9);
    #pragma unroll
    for (int t = 0; t < 8; t++){
        int c = lane + t * 64;
        float sn = (vals[t] - mu) * r * g[c] + bta[c];
        xp[c] = (tp[c] + sn + xp[c]) * (1.f / 3.f);
    }
}

// ---------------- row L2-normalize → bf16 hi/lo split
__global__ __launch_bounds__(256)
void rownorm_kernel(const float* __restrict__ in, ushort* __restrict__ XHp,
                    ushort* __restrict__ XLp){
    int wid = threadIdx.x >> 6, lane = threadIdx.x & 63;
    int row = blockIdx.x * 4 + wid;
    const float* p = in + ((size_t)row << 9);
    float vals[8]; float s2 = 0.f;
    #pragma unroll
    for (int t = 0; t < 8; t++){
        float v = p[lane + t * 64]; vals[t] = v; s2 += v * v;
    }
    #pragma unroll
    for (int off = 32; off; off >>= 1) s2 += __shfl_xor(s2, off, 64);
    float inv = 1.f / fmaxf(sqrtf(s2), 1e-8f);
    ushort* qh = XHp + ((size_t)row << 9);
    ushort* ql = XLp + ((size_t)row << 9);
    #pragma unroll
    for (int t = 0; t < 8; t++){
        float v = vals[t] * inv;
        ushort h = f2b(v);
        qh[lane + t * 64] = h;
        ql[lane + t * 64] = f2b(v - b2f(h));
    }
}

// ---------------- top-k: wave-per-row register selection, bitmask output
__global__ __launch_bounds__(256)
void topk_sel(const float* __restrict__ SIM, u64* __restrict__ MB){
    int wid = threadIdx.x >> 6, lane = threadIdx.x & 63;
    int r = blockIdx.x * 4 + wid;        // 0..B*LT-1
    int b = r / LT, i = r % LT;
    int bi, st, n; blk_info(i, bi, st, n);
    u64* mrow = MB + ((size_t)b * LT + i) * MBW;
    u64 myw = 0;
    if (lane == 21) myw = 0xFFFFFFFFFFFF0000ULL;     // pad: keys 1360..1407 banned
    if (n == 16){                                     // all 16 in-block keys banned
        if (lane == 21) myw = ~0ULL;
        if (lane < MBW) mrow[lane] = myw;
        return;
    }
    int goff = (bi == 0) ? SG0 : (bi == 1) ? SG1 : SG2;
    const float* srow = SIM + (size_t)b * SBT + goff + (size_t)(i - st) * n;
    int ns = n >> 6;
    float vals[16];
    #pragma unroll
    for (int t = 0; t < 16; t++)
        vals[t] = (t < ns) ? srow[lane + (t << 6)] : -FLT_MAX;
    for (int it = 0; it < 32; it++){
        float bv = vals[0]; int bt = 0;
        #pragma unroll
        for (int t = 1; t < 16; t++)
            if (vals[t] > bv){ bv = vals[t]; bt = t; }
        int bidx = (bt << 6) + lane;
        #pragma unroll
        for (int off = 1; off < 64; off <<= 1){
            float ov = __shfl_xor(bv, off, 64);
            int   oi = __shfl_xor(bidx, off, 64);
            if (ov > bv || (ov == bv && oi < bidx)){ bv = ov; bidx = oi; }
        }
        int gb = st + bidx;
        if (lane == (gb >> 6)) myw |= 1ULL << (gb & 63);
        if ((bidx & 63) == lane){
            int bt2 = bidx >> 6;
            #pragma unroll
            for (int t = 0; t < 16; t++) if (t == bt2) vals[t] = -FLT_MAX;
        }
    }
    if (lane < MBW) mrow[lane] = myw;
}

// ---------------- sparse temporal attention: prefetched, no-max exp2, coalesced V
__global__ __launch_bounds__(256)
void attn_sparse(const ushort* __restrict__ Q, const ushort* __restrict__ Kp,
                 const ushort* __restrict__ Vn, const int* __restrict__ IDX,
                 const int* __restrict__ CNT, float* __restrict__ O){
    int wid = threadIdx.x >> 6, lane = threadIdx.x & 63;
    int row = blockIdx.x * 4 + wid;
    int b = row / (NHH * LT);
    int rem = row % (NHH * LT);
    int h = rem / LT, i = rem % LT;
    int c = CNT[i];
    int jl = IDX[i * 12 + (lane % 12)];
    float qd = b2f(Q[(((size_t)b * LT + i) << 9) + h * 64 + lane]);
    const ushort* kb = Kp + (((size_t)b * LT) << 9) + h * 64 + lane;
    const ushort* vb = Vn + (((size_t)b * LT) << 9) + h * 64 + lane;
    int jj[12];
    #pragma unroll
    for (int t = 0; t < 12; t++) jj[t] = __shfl(jl, t, 64);
    float kv[12], vv[12];
    #pragma unroll
    for (int t = 0; t < 12; t++){
        kv[t] = b2f(kb[(size_t)jj[t] << 9]);
        vv[t] = b2f(vb[(size_t)jj[t] << 9]);
    }
    float lsum = 0.f, o = 0.f;
    #pragma unroll
    for (int t = 0; t < 12; t++){
        float s = qd * kv[t];
        #pragma unroll
        for (int off = 32; off; off >>= 1) s += __shfl_xor(s, off, 64);
        float p = (t < c) ? exp2f(s) : 0.f;
        lsum += p;
        o += p * vv[t];
    }
    O[(((size_t)b * LT + i) << 9) + h * 64 + lane] = o / lsum;
}

// ---------------- MFMA flash attention, 2-way split-K, XCD-swizzled
// grid (32 bh, 22 q-tiles, 2 halves): flattened%8 = bh%8 → per-XCD K/V locality.
// Writes UNNORMALIZED partial O (fp32) + partial l; flash_combine divides.
__global__ __launch_bounds__(256)
void flash_mfma(const ushort* __restrict__ Q, const ushort* __restrict__ Kp,
                const ushort* __restrict__ Vt, const u64* __restrict__ MB,
                float* __restrict__ FO0, float* __restrict__ FO1,
                float* __restrict__ LP)
{
    __shared__ ushort Ks[64][72];
    __shared__ ushort Vs[64][72];
    __shared__ u64 Ms64[64];
    __shared__ ushort Ps[4][16][72];
    int bh = blockIdx.x, b = bh >> 3, h = bh & 7;
    int q0 = blockIdx.y << 6;
    int half = blockIdx.z;
    int tid = threadIdx.x;
    int w = tid >> 6, lane = tid & 63, quad = lane >> 4, l15 = lane & 15;

    int qm = q0 + w * 16 + l15;
    int qmc = (qm < LT) ? qm : (LT - 1);
    const ushort* qp = Q + ((size_t)(b * LT + qmc) << 9) + h * 64 + (quad << 3);
    short8 qf0 = *(const short8*)qp;
    short8 qf1 = *(const short8*)(qp + 32);

    float l_acc[4] = {0.f, 0.f, 0.f, 0.f};
    f32x4 Oacc[4];
    #pragma unroll
    for (int dt = 0; dt < 4; dt++) Oacc[dt] = (f32x4){0.f,0.f,0.f,0.f};

    int srow = tid >> 2, sc = (tid & 3) << 4;
    const u64* Mbase = MB + (size_t)b * LT * MBW;

    int ktE = half * 11 + 11;
    for (int kt = half * 11; kt < ktE; kt++){
        int k0 = kt << 6;
        __syncthreads();
        {
            int krow = k0 + srow; if (krow >= LT) krow = LT - 1;
            const ushort* kp = Kp + ((size_t)(b * LT + krow) << 9) + h * 64 + sc;
            *(uint4*)&Ks[srow][sc]     = *(const uint4*)kp;
            *(uint4*)&Ks[srow][sc + 8] = *(const uint4*)(kp + 8);
            int kbase = k0 + sc; if (kbase > LT - 16) kbase = LT - 16;
            const ushort* vp = Vt + ((size_t)(b * 512 + h * 64 + srow)) * LT + kbase;
            *(uint4*)&Vs[srow][sc]     = *(const uint4*)vp;
            *(uint4*)&Vs[srow][sc + 8] = *(const uint4*)(vp + 8);
            if (tid < 64){
                int mrow = q0 + tid; if (mrow >= LT) mrow = LT - 1;
                Ms64[tid] = Mbase[(size_t)mrow * MBW + kt];
            }
        }
        __syncthreads();
        f32x4 s[4];
        #pragma unroll
        for (int nt = 0; nt < 4; nt++) s[nt] = (f32x4){0.f,0.f,0.f,0.f};
        #pragma unroll
        for (int nt = 0; nt < 4; nt++){
            short8 kf0 = *(const short8*)&Ks[(nt << 4) + l15][quad << 3];
            short8 kf1 = *(const short8*)&Ks[(nt << 4) + l15][32 + (quad << 3)];
            s[nt] = __builtin_amdgcn_mfma_f32_16x16x32_bf16(qf0, kf0, s[nt], 0, 0, 0);
            s[nt] = __builtin_amdgcn_mfma_f32_16x16x32_bf16(qf1, kf1, s[nt], 0, 0, 0);
        }
        #pragma unroll
        for (int r = 0; r < 4; r++){
            int lrow = (w << 4) + (quad << 2) + r;
            u64 bits = Ms64[lrow];
            float psum = 0.f;
            #pragma unroll
            for (int nt = 0; nt < 4; nt++){
                uint32_t bad = (uint32_t)(bits >> (nt * 16 + l15)) & 1u;
                float pv = bad ? 0.f : exp2f(s[nt][r]);
                psum += pv;
                Ps[w][(quad << 2) + r][(nt << 4) + l15] = f2b(pv);
            }
            l_acc[r] += psum;
        }
        short8 pf0 = *(const short8*)&Ps[w][l15][quad << 3];
        short8 pf1 = *(const short8*)&Ps[w][l15][32 + (quad << 3)];
        #pragma unroll
        for (int dt = 0; dt < 4; dt++){
            short8 vf0 = *(const short8*)&Vs[(dt << 4) + l15][quad << 3];
            short8 vf1 = *(const short8*)&Vs[(dt << 4) + l15][32 + (quad << 3)];
            Oacc[dt] = __builtin_amdgcn_mfma_f32_16x16x32_bf16(pf0, vf0, Oacc[dt], 0, 0, 0);
            Oacc[dt] = __builtin_amdgcn_mfma_f32_16x16x32_bf16(pf1, vf1, Oacc[dt], 0, 0, 0);
        }
    }
    #pragma unroll
    for (int r = 0; r < 4; r++){
        #pragma unroll
        for (int off = 1; off < 16; off <<= 1)
            l_acc[r] += __shfl_xor(l_acc[r], off, 64);
    }
    float* FO = half ? FO1 : FO0;
    float* Lp = LP + (size_t)half * BB * NHH * LT;
    #pragma unroll
    for (int r = 0; r < 4; r++){
        int qrow = q0 + (w << 4) + (quad << 2) + r;
        if (qrow < LT){
            #pragma unroll
            for (int dt = 0; dt < 4; dt++)
                FO[((size_t)(b * LT + qrow) << 9) + h * 64 + (dt << 4) + l15] = Oacc[dt][r];
            if (l15 == 0)
                Lp[(size_t)(b * NHH + h) * LT + qrow] = l_acc[r];
        }
    }
}

// ---------------- combine flash halves: AO = (FO0+FO1)/(l0+l1)
__global__ __launch_bounds__(256)
void flash_combine(const float* __restrict__ FO0, const float* __restrict__ FO1,
                   const float* __restrict__ LP, float* __restrict__ AO){
    int wid = threadIdx.x >> 6, lane = threadIdx.x & 63;
    int row = blockIdx.x * 4 + wid;       // 0..B*LT-1
    int b = row / LT, q = row % LT;
    size_t base = (size_t)row << 9;
    const float* Lp0 = LP;
    const float* Lp1 = LP + (size_t)BB * NHH * LT;
    #pragma unroll
    for (int t = 0; t < 8; t++){          // h = t
        size_t li = (size_t)(b * NHH + t) * LT + q;
        float inv = 1.f / (Lp0[li] + Lp1[li]);
        int c = lane + t * 64;
        AO[base + c] = (FO0[base + c] + FO1[base + c]) * inv;
    }
}

extern "C" void kernel_launch(void* const* d_in, const int* in_sizes, int n_in,
                              void* d_out, int out_size, void* d_ws, size_t ws_size,
                              hipStream_t stream)
{
    const float* x_enc   = (const float*)d_in[0];
    const float* down_W  = (const float*)d_in[1];
    const float* down_b  = (const float*)d_in[2];
    const float* conv_W  = (const float*)d_in[3];
    const float* conv_b  = (const float*)d_in[4];
    const float* up_W    = (const float*)d_in[5];
    const float* up_b    = (const float*)d_in[6];
    const float* bc_g    = (const float*)d_in[7];
    const float* bc_b    = (const float*)d_in[8];
    const float* aWq     = (const float*)d_in[9];
    const float* aWk     = (const float*)d_in[10];
    const float* aWv     = (const float*)d_in[11];
    const float* afcW    = (const float*)d_in[12];
    const float* afcb    = (const float*)d_in[13];
    const float* alng    = (const float*)d_in[14];
    const float* alnb    = (const float*)d_in[15];
    const float* fW1     = (const float*)d_in[16];
    const float* fb1     = (const float*)d_in[17];
    const float* fW2     = (const float*)d_in[18];
    const float* fb2     = (const float*)d_in[19];
    const float* flng    = (const float*)d_in[20];
    const float* flnb    = (const float*)d_in[21];

    const size_t NBL = (size_t)NBLE;
    float* X   = (float*)d_ws;
    float* TMP = X   + NBL;
    float* Qb  = TMP + NBL;
    float* Kb  = Qb  + NBL;
    float* Vb  = Kb  + NBL;
    float* AO  = Vb  + NBL;
    float* TO  = AO  + NBL;
    float* SO  = TO  + NBL;
    u64* MBm = (u64*)(SO + NBL);                      // B*LT*24 words
    int* TIDX = (int*)(MBm + (size_t)BB * LT * MBW);
    int* TCNT = TIDX + (size_t)LT * 12;
    ushort* WG = (ushort*)(TCNT + LT);
    const size_t M512 = 262144;
    ushort* WdownT = WG;                 size_t wo = M512;
    ushort* WupT   = WG + wo;            wo += M512;
    ushort* Wqkv   = WG + wo;            wo += 12 * M512;   // 4 layers x [Wq|Wk|Wv]^T
    ushort* WfT    = WG + wo;            wo += 4 * M512;
    ushort* W1T    = WG + wo;            wo += 2 * M512;
    ushort* W2T    = WG + wo;            wo += 2 * M512;
    ushort* WCt    = WG + wo;            wo += 3 * 1048576;
    float* LP = (float*)(WG + wo);                        // 2 * B*NHH*LT fp32 l-partials
    size_t need = 8 * NBL * sizeof(float) + (size_t)BB * LT * MBW * 8
                + (size_t)LT * 13 * 4 + wo * sizeof(ushort)
                + (size_t)2 * BB * NHH * LT * 4;
    if (ws_size < need) return;

    // aliases (lifetimes disjoint)
    float* Y    = Qb;
    float* C1   = Kb;
    float* C2   = C1 + (size_t)BB*256*512;
    float* C3   = C2 + (size_t)BB*64*512;
    float* PCAT = Vb;
    float* SKP  = AO;                     // split-K partials (bottleneck only)
    ushort* XNh = (ushort*)AO;            // hi/lo bf16 normalized rows
    ushort* XNl = XNh + NBL;
    float* SIMB = Qb;
    float* Hf   = Qb;
    ushort* QbH = (ushort*)Qb;
    ushort* KbH = (ushort*)Kb;
    ushort* VtH = (ushort*)Vb;            // V^T in first half of Vb
    ushort* VnH = VtH + NBL;              // V normal layout in second half of Vb
    float* FO0  = TMP;                    // flash partials (TMP/SO free during flash)
    float* FO1  = SO;

    auto gemmB = [&](const float* A, const ushort* Bw, const float* bias,
                     const float* res, void* C, int M, int N, int K,
                     int act, int omode, int mpb, int orpb, int ooff){
        dim3 grid(N / 128, M / 64);
        gemm_bf16<<<grid, 256, 0, stream>>>(A, Bw, bias, res, C, M, N, K,
                                            act, omode, mpb, orpb, ooff);
    };
    auto gemmN = [&](const float* A, const ushort* Bw, const float* bias,
                     const float* res, void* C, int M, int K,
                     int act, int omode, int mpb, int orpb, int ooff){
        dim3 grid(8, M / 64);
        gemm64<<<grid, 256, 0, stream>>>(A, Bw, bias, res, C, M, 512, K,
                                         act, omode, mpb, orpb, ooff);
    };
    auto convG = [&](const float* A, const ushort* Bw, const float* bias,
                     float* C, int M){
        const int S = 8, K = 2048, N = 512;
        gemm_sk<<<dim3(8, M / 64, S), 256, 0, stream>>>(A, Bw, SKP, M, N, K, K / S);
        sk_reduce<<<(M * N) / 1024, 256, 0, stream>>>(SKP, bias, C, M * N, S);
    };

    build_tidx<<<(LT + 255) / 256, 256, 0, stream>>>(TIDX, TCNT);
    wtrans<<<dim3(8, 8, 1), 256, 0, stream>>>(down_W, WdownT, 512, 512, M512);
    wtrans<<<dim3(8, 8, 1), 256, 0, stream>>>(up_W,   WupT,   512, 512, M512);
    wtrans<<<dim3(8, 8, 4), 256, 0, stream>>>(aWq,  Wqkv + 0 * M512, 512, 512, 3 * (long)M512);
    wtrans<<<dim3(8, 8, 4), 256, 0, stream>>>(aWk,  Wqkv + 1 * M512, 512, 512, 3 * (long)M512);
    wtrans<<<dim3(8, 8, 4), 256, 0, stream>>>(aWv,  Wqkv + 2 * M512, 512, 512, 3 * (long)M512);
    wtrans<<<dim3(8, 8, 4), 256, 0, stream>>>(afcW, WfT, 512, 512, M512);
    wtrans<<<dim3(8, 8, 2), 256, 0, stream>>>(fW1,  W1T, 512, 512, M512);
    wtrans<<<dim3(8, 8, 2), 256, 0, stream>>>(fW2,  W2T, 512, 512, M512);
    wconv<<<dim3(4096, 3), 256, 0, stream>>>(conv_W, WCt);

    // ---- bottleneck
    gemmN(x_enc, WdownT, down_b, nullptr, Y, BB*1024, 512, 0, 0, 0, 0, 0);
    convG(Y,  WCt,             conv_b + 0,    C1, BB*256);
    convG(C1, WCt + 1048576,   conv_b + 512,  C2, BB*64);
    convG(C2, WCt + 2*1048576, conv_b + 1024, C3, BB*16);
    pcat_copy<<<(BB*336*512)/256, 256, 0, stream>>>(C1, C2, C3, PCAT);
    gemmN(PCAT, WupT, up_b, nullptr, TMP, BB*336, 512, 0, 0, 336, LT, 1024);
    xenc_copy<<<(BB*1024*512)/256, 256, 0, stream>>>(x_enc, TMP);
    ln_kernel<<<(BB*LT)/4, 256, 0, stream>>>(TMP, bc_g, bc_b, X, 1e-5f);

    // ---- transformer layers
    for (int l = 0; l < 2; l++){
        rownorm_kernel<<<(BB*LT)/4, 256, 0, stream>>>(X, XNh, XNl);
        sim_mfma<<<dim3(274, BB), 256, 0, stream>>>(XNh, XNl, SIMB);
        topk_sel<<<(BB*LT)/4, 256, 0, stream>>>(SIMB, MBm);

        for (int j = 0; j < 2; j++){
            int li = l * 2 + j;
            const float* bf = afcb + (size_t)li * 512;
            const float* lg = alng + (size_t)li * 512;
            const float* lb = alnb + (size_t)li * 512;
            // fused QKV projection: Q(scaled)->QbH, K->KbH, V^T->VtH, V->VnH
            gemmB(X, Wqkv + (size_t)li * 3 * M512, nullptr, nullptr, QbH,
                  BB*LT, 1536, 512, 0, 3, 0, 0, 0);
            if (j == 0){
                attn_sparse<<<(BB*NHH*LT)/4, 256, 0, stream>>>(QbH, KbH, VnH, TIDX, TCNT, AO);
            } else {
                flash_mfma<<<dim3(32, 22, 2), 256, 0, stream>>>(QbH, KbH, VtH, MBm, FO0, FO1, LP);
                flash_combine<<<(BB*LT)/4, 256, 0, stream>>>(FO0, FO1, LP, AO);
            }
            gemmN(AO, WfT + (size_t)li * M512, bf, X, TMP, BB*LT, 512, 0, 0, 0, 0, 0);
            if (j == 0)
                ln_kernel<<<(BB*LT)/4, 256, 0, stream>>>(TMP, lg, lb, TO, 1e-6f);
            else
                ln_add3<<<(BB*LT)/4, 256, 0, stream>>>(TMP, lg, lb, TO, X, 1e-6f);
        }

        // FFN
        gemmN(X,  W1T + (size_t)l * M512, fb1 + (size_t)l*512, nullptr, Hf, BB*LT, 512, 2, 0, 0, 0, 0);
        gemmN(Hf, W2T + (size_t)l * M512, fb2 + (size_t)l*512, X, TMP, BB*LT, 512, 0, 0, 0, 0, 0);
        ln_kernel<<<(BB*LT)/4, 256, 0, stream>>>(TMP, flng + (size_t)l*512, flnb + (size_t)l*512,
                                                 (l == 1) ? (float*)d_out : X, 1e-6f);
    }
}